// Round 7
// baseline (292.684 us; speedup 1.0000x reference)
//
#include <hip/hip_runtime.h>
#include <math.h>

#define NN 1500
#define BB 8
#define TT 32
#define HIDD 32
#define BOTT 8
#define CC 16
#define NHEADS 4
#define NSCALES 4
#define HZNN 12
#define BC (BB*HIDD)   // 256 columns for diffusion SPMM
#define CAP 128        // max nnz per adjacency row (mean ~16)
#define MC 128         // attention K/V chunk rows staged in LDS
#define MSPLIT 2       // attention m-dimension splits (dense)
#define RT 128         // attention rows per block (32 groups x 4 rows)
#define NTILES 12      // ceil(1500/128)
#define PROWS (NTILES*RT)  // 1536 padded rows in partial buffer

// ---------------- fused: prep (blocks 0..NN-1) + temporal (blocks NN..) ----------------
__global__ void k_prep_temporal(const float* __restrict__ adj,
                                const float* __restrict__ gV,
                                int* __restrict__ sidx, float* __restrict__ sval,
                                float* __restrict__ sraw, int* __restrict__ scnt,
                                float* __restrict__ VgT,
                                const float* __restrict__ x,
    const float* __restrict__ dw_w, const float* __restrict__ dw_b,
    const float* __restrict__ bn1_g, const float* __restrict__ bn1_b,
    const float* __restrict__ pw_w, const float* __restrict__ pw_b,
    const float* __restrict__ bn2_g, const float* __restrict__ bn2_b,
    const float* __restrict__ feat_w, const float* __restrict__ feat_b,
    float* __restrict__ h0) {
  if (blockIdx.x < NN) {
    int n = blockIdx.x;
    int tid = threadIdx.x;
    const float* row = adj + (size_t)n * NN;
    __shared__ int cnt;
    __shared__ float red[4];
    __shared__ float s_inv;
    float ssum = 0.f;
    for (int m = tid; m < NN; m += 256) ssum += row[m];
    for (int off = 32; off > 0; off >>= 1) ssum += __shfl_down(ssum, off, 64);
    if ((tid & 63) == 0) red[tid >> 6] = ssum;
    if (tid == 0) cnt = 0;
    __syncthreads();
    if (tid == 0) {
      float tot = red[0] + red[1] + red[2] + red[3] + 1.0f;
      s_inv = 1.0f / (tot + 1e-8f);
    }
    __syncthreads();
    float inv = s_inv;
    for (int m = tid; m < NN; m += 256) {
      float a = row[m];
      if (a != 0.f || m == n) {
        int pos = atomicAdd(&cnt, 1);
        if (pos < CAP) {
          sidx[n * CAP + pos] = m;
          sval[n * CAP + pos] = (a + (m == n ? 1.f : 0.f)) * inv;
          sraw[n * CAP + pos] = a;
        }
      }
    }
    __syncthreads();
    if (tid == 0) scnt[n] = min(cnt, CAP);
    if (n == 0) {
      for (int m = tid; m < NN; m += 256) {
#pragma unroll
        for (int j = 0; j < 8; ++j) VgT[m * 8 + j] = gV[j * NN + m];
      }
    }
  } else {
    int tid = (blockIdx.x - NN) * 256 + threadIdx.x;
    if (tid >= BB * NN) return;
    int b = tid / NN, n = tid % NN;
    float s[TT];
#pragma unroll
    for (int t = 0; t < TT; ++t) s[t] = x[(size_t)b * TT * NN + (size_t)t * NN + n];
    float w0 = dw_w[0], w1 = dw_w[1], w2 = dw_w[2];
    float db = dw_b[0], g1v = bn1_g[0], b1v = bn1_b[0];
    float dwr[TT];
#pragma unroll
    for (int t = 0; t < TT; ++t) {
      float left  = (t > 0)      ? s[t - 1] : 0.f;
      float right = (t < TT - 1) ? s[t + 1] : 0.f;
      float v = left * w0 + s[t] * w1 + right * w2;
      v = (v + db) * g1v + b1v;
      dwr[t] = fmaxf(v, 0.f);
    }
    float mo[CC];
#pragma unroll
    for (int o = 0; o < CC; ++o) mo[o] = 0.f;
    for (int t = 0; t < TT; ++t) {
      float d = dwr[t];
#pragma unroll
      for (int o = 0; o < CC; ++o) {
        float v = (d * pw_w[o] + pw_b[o]) * bn2_g[o] + bn2_b[o];
        mo[o] += fmaxf(v, 0.f);
      }
    }
#pragma unroll
    for (int o = 0; o < CC; ++o) mo[o] *= (1.f / TT);
    float* dst = h0 + (size_t)n * BC + b * HIDD;
    for (int j = 0; j < HIDD; ++j) {
      float acc = feat_b[j];
#pragma unroll
      for (int o = 0; o < CC; ++o) acc += mo[o] * feat_w[o * HIDD + j];
      dst[j] = acc;
    }
  }
}

// ---------------- sparse diffusion: Y[n,:] = sum_e val_e * X[idx_e,:] ----------------
__global__ void k_spmm_sp(const int* __restrict__ sidx, const float* __restrict__ sval,
                          const int* __restrict__ scnt,
                          const float* __restrict__ X, float* __restrict__ Y) {
  int n = blockIdx.x;
  int tid = threadIdx.x;
  __shared__ int   li[CAP];
  __shared__ float lv[CAP];
  int cnt = scnt[n];
  if (tid < cnt) { li[tid] = sidx[n * CAP + tid]; lv[tid] = sval[n * CAP + tid]; }
  __syncthreads();
  float acc = 0.f;
  for (int e = 0; e < cnt; ++e) acc += lv[e] * X[(size_t)li[e] * BC + tid];
  Y[(size_t)n * BC + tid] = acc;
}

// ---------------- multi-scale fusion + sp_ln + qkv: 16 lanes per row ----------------
// 750 blocks x 16 rows -> 3000 waves (~12/CU) to hide the dependent-chain latency.
__global__ void k_fuse_qkv(
    const float* __restrict__ h0, const float* __restrict__ g1,
    const float* __restrict__ g2, const float* __restrict__ g3,
    const float* __restrict__ scale_w, const float* __restrict__ scale_b,
    const float* __restrict__ sln_g, const float* __restrict__ sln_b,
    const float* __restrict__ fusion_w,
    const float* __restrict__ fus_lo_w, const float* __restrict__ fus_lo_b,
    const float* __restrict__ fus_hi_w, const float* __restrict__ fus_hi_b,
    const float* __restrict__ sp_g, const float* __restrict__ sp_b,
    const float* __restrict__ qkv_lo_w, const float* __restrict__ qkv_lo_b,
    const float* __restrict__ qkv_hi_w, const float* __restrict__ qkv_hi_b,
    float* __restrict__ h_out,
    float* __restrict__ Qw, float* __restrict__ Kw, float* __restrict__ Vw) {
  int tid = threadIdx.x;
  int gr = tid >> 4, l = tid & 15;
  int row = blockIdx.x * 16 + gr;          // 750 blocks * 16 rows = 12000
  int b = row / NN, n = row % NN;
  size_t rofs = (size_t)n * BC + b * HIDD;
  int j0 = 2 * l;                          // this lane's 2 output dims
  float fw0 = fusion_w[0], fw1 = fusion_w[1], fw2 = fusion_w[2], fw3 = fusion_w[3];
  float fm = fmaxf(fmaxf(fw0, fw1), fmaxf(fw2, fw3));
  float e0 = __expf(fw0 - fm), e1 = __expf(fw1 - fm), e2 = __expf(fw2 - fm), e3 = __expf(fw3 - fm);
  float einv = 1.f / (e0 + e1 + e2 + e3);
  float alpha[4] = {e0 * einv, e1 * einv, e2 * einv, e3 * einv};
  const float* srcp[4] = {h0, g1, g2, g3};
  float fused[2] = {0.f, 0.f};
#pragma unroll
  for (int i = 0; i < NSCALES; ++i) {
    const float* sp = srcp[i] + rofs;
    float src[32];
#pragma unroll
    for (int k4 = 0; k4 < 8; ++k4) {
      float4 f = *(const float4*)(sp + k4 * 4);
      src[k4 * 4] = f.x; src[k4 * 4 + 1] = f.y; src[k4 * 4 + 2] = f.z; src[k4 * 4 + 3] = f.w;
    }
    const float* W = scale_w + i * HIDD * HIDD;
    float t0 = scale_b[i * HIDD + j0], t1v = scale_b[i * HIDD + j0 + 1];
#pragma unroll
    for (int k = 0; k < 32; ++k) {
      float2 w = *(const float2*)(W + k * HIDD + j0);
      t0 += src[k] * w.x; t1v += src[k] * w.y;
    }
    float s1 = t0 + t1v;
    float s2 = t0 * t0 + t1v * t1v;
    s1 += __shfl_xor(s1, 1, 16); s1 += __shfl_xor(s1, 2, 16);
    s1 += __shfl_xor(s1, 4, 16); s1 += __shfl_xor(s1, 8, 16);
    s2 += __shfl_xor(s2, 1, 16); s2 += __shfl_xor(s2, 2, 16);
    s2 += __shfl_xor(s2, 4, 16); s2 += __shfl_xor(s2, 8, 16);
    float mean = s1 * (1.f / 32.f);
    float var = s2 * (1.f / 32.f) - mean * mean;
    float r = rsqrtf(var + 1e-5f);
    float a = alpha[i];
    float tn0 = (t0 - mean) * r * sln_g[i * HIDD + j0] + sln_b[i * HIDD + j0];
    float tn1 = (t1v - mean) * r * sln_g[i * HIDD + j0 + 1] + sln_b[i * HIDD + j0 + 1];
    fused[0] += a * fmaxf(tn0, 0.f);
    fused[1] += a * fmaxf(tn1, 0.f);
  }
  float lo[BOTT];
#pragma unroll
  for (int o = 0; o < BOTT; ++o) {
    float acc = fused[0] * fus_lo_w[j0 * BOTT + o] + fused[1] * fus_lo_w[(j0 + 1) * BOTT + o];
    acc += __shfl_xor(acc, 1, 16); acc += __shfl_xor(acc, 2, 16);
    acc += __shfl_xor(acc, 4, 16); acc += __shfl_xor(acc, 8, 16);
    lo[o] = acc + fus_lo_b[o];
  }
  float2 hv2 = *(const float2*)(h0 + rofs + j0);
  float pre[2] = {hv2.x, hv2.y};
#pragma unroll
  for (int jj = 0; jj < 2; ++jj) {
    float acc = fus_hi_b[j0 + jj] + pre[jj];
#pragma unroll
    for (int o = 0; o < BOTT; ++o) acc += lo[o] * fus_hi_w[o * HIDD + j0 + jj];
    pre[jj] = acc;
  }
  {
    float s1 = pre[0] + pre[1];
    float s2 = pre[0] * pre[0] + pre[1] * pre[1];
    s1 += __shfl_xor(s1, 1, 16); s1 += __shfl_xor(s1, 2, 16);
    s1 += __shfl_xor(s1, 4, 16); s1 += __shfl_xor(s1, 8, 16);
    s2 += __shfl_xor(s2, 1, 16); s2 += __shfl_xor(s2, 2, 16);
    s2 += __shfl_xor(s2, 4, 16); s2 += __shfl_xor(s2, 8, 16);
    float mean = s1 * (1.f / 32.f);
    float var = s2 * (1.f / 32.f) - mean * mean;
    float r = rsqrtf(var + 1e-5f);
#pragma unroll
    for (int jj = 0; jj < 2; ++jj)
      pre[jj] = (pre[jj] - mean) * r * sp_g[j0 + jj] + sp_b[j0 + jj];
  }
  *(float2*)(h_out + (size_t)row * HIDD + j0) = make_float2(pre[0], pre[1]);
  float t1[24];
#pragma unroll
  for (int o = 0; o < 24; ++o) {
    float acc = pre[0] * qkv_lo_w[j0 * 24 + o] + pre[1] * qkv_lo_w[(j0 + 1) * 24 + o];
    acc += __shfl_xor(acc, 1, 16); acc += __shfl_xor(acc, 2, 16);
    acc += __shfl_xor(acc, 4, 16); acc += __shfl_xor(acc, 8, 16);
    t1[o] = acc + qkv_lo_b[o];
  }
  // qkv_hi: 96 outputs over 16 lanes: lane = (sub,d); sub selects head pair, d the dim
  int sub = l >> 3, d = l & 7;
#pragma unroll
  for (int part = 0; part < 3; ++part) {
    float* dst = (part == 0) ? Qw : (part == 1) ? Kw : Vw;
#pragma unroll
    for (int hh = 0; hh < 2; ++hh) {
      int hd = sub * 2 + hh;
      int p = part * 32 + hd * 8 + d;
      float acc = qkv_hi_b[p];
#pragma unroll
      for (int o = 0; o < 24; ++o) acc += t1[o] * qkv_hi_w[o * 96 + p];
      dst[(((size_t)b * NHEADS + hd) * NN + n) * 8 + d] = acc;
    }
  }
}

// ---------------- attention: q'=[q/sqrt8,U], k'=[k,Vg]; 4 rows/lane amortizes LDS ----
// __launch_bounds__(256,2): ~256 VGPR budget. r6 showed (256,3) -> 76 VGPRs with the
// acc[4][8]+qv[4][16] state pushed into AGPRs, tripling the inner-loop acc updates
// (v_accvgpr_read+fma+write). 2 waves/EU keeps everything in VGPRs; kernel is
// VALU-throughput-bound so 8 waves/CU suffices.
// grid = (32 bh, 12 tiles, MSPLIT+1). z<MSPLIT: dense partial; z==MSPLIT: sparse correction.
// Partial buffer P[z][bh][PROWS][12]: [0..7]=acc, [8]=sum.
__global__ void __launch_bounds__(256, 2)
k_attn(const float* __restrict__ Qw, const float* __restrict__ Kw,
       const float* __restrict__ Vw,
       const float* __restrict__ gU, const float* __restrict__ VgT,
       const int* __restrict__ sidx, const float* __restrict__ sraw,
       const int* __restrict__ scnt,
       const float* __restrict__ adj_mix, const float* __restrict__ adj_scale,
       float* __restrict__ P) {
  int bh = blockIdx.x, tile = blockIdx.y, z = blockIdx.z;
  int tid = threadIdx.x;
  int g = tid >> 3, p = tid & 7;
  __shared__ float Ks[MC * 20];   // 16 floats K' + 4 pad
  __shared__ float Vs[MC * 12];   // 8 floats V + 4 pad
  const float scl = 0.35355339059327373f;  // 1/sqrt(8)
  float qv[4][16], acc[4][8], sm[4];
  int nrow[4];
#pragma unroll
  for (int rr = 0; rr < 4; ++rr) {
    int n = tile * RT + g * 4 + rr;
    nrow[rr] = n;
    int nc = (n < NN) ? n : NN - 1;
    const float* qp = Qw + ((size_t)bh * NN + nc) * 8;
    float4 q0 = *(const float4*)qp;
    float4 q1 = *(const float4*)(qp + 4);
    const float* up = gU + nc * 8;
    float4 u0 = *(const float4*)up;
    float4 u1 = *(const float4*)(up + 4);
    qv[rr][0] = q0.x * scl; qv[rr][1] = q0.y * scl; qv[rr][2] = q0.z * scl; qv[rr][3] = q0.w * scl;
    qv[rr][4] = q1.x * scl; qv[rr][5] = q1.y * scl; qv[rr][6] = q1.z * scl; qv[rr][7] = q1.w * scl;
    qv[rr][8] = u0.x; qv[rr][9] = u0.y; qv[rr][10] = u0.z; qv[rr][11] = u0.w;
    qv[rr][12] = u1.x; qv[rr][13] = u1.y; qv[rr][14] = u1.z; qv[rr][15] = u1.w;
    sm[rr] = 0.f;
#pragma unroll
    for (int d = 0; d < 8; ++d) acc[rr][d] = 0.f;
  }
  if (z < MSPLIT) {
    const int mcount = NN / MSPLIT;          // 750
    const int mbase = z * mcount;
    const float* Kb = Kw + (size_t)bh * NN * 8;
    const float* Vb = Vw + (size_t)bh * NN * 8;
    for (int c0 = 0; c0 < mcount; c0 += MC) {
      int mlen = min(MC, mcount - c0);
      __syncthreads();
      {
        int mm = tid >> 1, hh = tid & 1;
        float4 kf = make_float4(0.f,0.f,0.f,0.f), gf = kf, vf = kf;
        if (mm < mlen) {
          int m = mbase + c0 + mm;
          kf = *(const float4*)(Kb + (size_t)m * 8 + hh * 4);
          gf = *(const float4*)(VgT + (size_t)m * 8 + hh * 4);
          vf = *(const float4*)(Vb + (size_t)m * 8 + hh * 4);
        }
        *(float4*)(Ks + mm * 20 + hh * 4) = kf;
        *(float4*)(Ks + mm * 20 + 8 + hh * 4) = gf;
        *(float4*)(Vs + mm * 12 + hh * 4) = vf;
      }
      __syncthreads();
#pragma unroll 2
      for (int i = 0; i < MC / 8; ++i) {
        int mm = p + i * 8;
        const float* kp = Ks + mm * 20;
        float4 k0 = *(const float4*)(kp);
        float4 k1 = *(const float4*)(kp + 4);
        float4 k2 = *(const float4*)(kp + 8);
        float4 k3 = *(const float4*)(kp + 12);
        const float* vp = Vs + mm * 12;
        float4 v0 = *(const float4*)(vp);
        float4 v1 = *(const float4*)(vp + 4);
#pragma unroll
        for (int rr = 0; rr < 4; ++rr) {
          float s = qv[rr][0]*k0.x + qv[rr][1]*k0.y + qv[rr][2]*k0.z + qv[rr][3]*k0.w
                  + qv[rr][4]*k1.x + qv[rr][5]*k1.y + qv[rr][6]*k1.z + qv[rr][7]*k1.w
                  + qv[rr][8]*k2.x + qv[rr][9]*k2.y + qv[rr][10]*k2.z + qv[rr][11]*k2.w
                  + qv[rr][12]*k3.x + qv[rr][13]*k3.y + qv[rr][14]*k3.z + qv[rr][15]*k3.w;
          float e = __expf(s);
          sm[rr] += e;
          acc[rr][0] += e * v0.x; acc[rr][1] += e * v0.y; acc[rr][2] += e * v0.z; acc[rr][3] += e * v0.w;
          acc[rr][4] += e * v1.x; acc[rr][5] += e * v1.y; acc[rr][6] += e * v1.z; acc[rr][7] += e * v1.w;
        }
      }
      if (mlen < MC) {
        // padded rows contributed exactly exp(0)=1 to sm (V=0): subtract analytically
        int npad = (MC / 8) - ((mlen - p + 7) >> 3);
#pragma unroll
        for (int rr = 0; rr < 4; ++rr) sm[rr] -= (float)npad;
      }
    }
  } else {
    // sparse adjacency correction: e_true = e' * exp(smix*a) for adj nnz
    float smix = adj_scale[0] / (1.f + __expf(-adj_mix[0]));
    const float* Kb = Kw + (size_t)bh * NN * 8;
    const float* Vb = Vw + (size_t)bh * NN * 8;
#pragma unroll
    for (int rr = 0; rr < 4; ++rr) {
      int n = nrow[rr];
      if (n < NN) {
        int cnt = scnt[n];
        for (int e = p; e < cnt; e += 8) {
          int m = sidx[n * CAP + e];
          float a = sraw[n * CAP + e];
          if (a != 0.f) {
            const float* kp = Kb + (size_t)m * 8;
            float4 k0 = *(const float4*)(kp);
            float4 k1 = *(const float4*)(kp + 4);
            const float* gp = VgT + (size_t)m * 8;
            float4 k2 = *(const float4*)(gp);
            float4 k3 = *(const float4*)(gp + 4);
            float s = qv[rr][0]*k0.x + qv[rr][1]*k0.y + qv[rr][2]*k0.z + qv[rr][3]*k0.w
                    + qv[rr][4]*k1.x + qv[rr][5]*k1.y + qv[rr][6]*k1.z + qv[rr][7]*k1.w
                    + qv[rr][8]*k2.x + qv[rr][9]*k2.y + qv[rr][10]*k2.z + qv[rr][11]*k2.w
                    + qv[rr][12]*k3.x + qv[rr][13]*k3.y + qv[rr][14]*k3.z + qv[rr][15]*k3.w;
            float ep = __expf(s);
            float dlt = ep * (__expf(smix * a) - 1.f);
            sm[rr] += dlt;
            const float* vp = Vb + (size_t)m * 8;
            float4 v0 = *(const float4*)(vp);
            float4 v1 = *(const float4*)(vp + 4);
            acc[rr][0] += dlt * v0.x; acc[rr][1] += dlt * v0.y; acc[rr][2] += dlt * v0.z; acc[rr][3] += dlt * v0.w;
            acc[rr][4] += dlt * v1.x; acc[rr][5] += dlt * v1.y; acc[rr][6] += dlt * v1.z; acc[rr][7] += dlt * v1.w;
          }
        }
      }
    }
  }
#pragma unroll
  for (int rr = 0; rr < 4; ++rr) {
    float s = sm[rr];
    s += __shfl_xor(s, 1, 8); s += __shfl_xor(s, 2, 8); s += __shfl_xor(s, 4, 8);
#pragma unroll
    for (int d = 0; d < 8; ++d) {
      acc[rr][d] += __shfl_xor(acc[rr][d], 1, 8);
      acc[rr][d] += __shfl_xor(acc[rr][d], 2, 8);
      acc[rr][d] += __shfl_xor(acc[rr][d], 4, 8);
    }
    float val = acc[rr][0];
#pragma unroll
    for (int d = 1; d < 8; ++d) if (p == d) val = acc[rr][d];
    if (nrow[rr] < NN) {
      float* dst = P + ((size_t)(z * 32 + bh) * PROWS + nrow[rr]) * 12;
      dst[p] = val;
      if (p == 0) dst[8] = s;
    }
  }
}

// ---------------- merge partials + output proj + at_ln + gated predictor: 8 lanes/row ----
__global__ void k_final(const float* __restrict__ P, const float* __restrict__ h_in,
    const float* __restrict__ x,
    const float* __restrict__ out_lo_w, const float* __restrict__ out_lo_b,
    const float* __restrict__ out_hi_w, const float* __restrict__ out_hi_b,
    const float* __restrict__ at_g, const float* __restrict__ at_b,
    const float* __restrict__ pred_lo_w, const float* __restrict__ pred_lo_b,
    const float* __restrict__ mid_g, const float* __restrict__ mid_b,
    const float* __restrict__ pred_hi_w, const float* __restrict__ pred_hi_b,
    const float* __restrict__ log_decay,
    const float* __restrict__ gate_w1, const float* __restrict__ gate_b1,
    const float* __restrict__ gate_w2, const float* __restrict__ gate_b2,
    float* __restrict__ out) {
  int tid = threadIdx.x;
  int gr = tid >> 3, l = tid & 7;
  int row = blockIdx.x * 32 + gr;   // 375 blocks * 32 rows = 12000
  int b = row / NN, n = row % NN;
  int j0 = 4 * l;
  int hd = l >> 1, d0 = (l & 1) * 4;
  int bh = b * NHEADS + hd;
  float av[4] = {0.f, 0.f, 0.f, 0.f};
  float smt = 0.f;
#pragma unroll
  for (int z = 0; z <= MSPLIT; ++z) {
    const float* q = P + ((size_t)(z * 32 + bh) * PROWS + n) * 12;
    float4 a4 = *(const float4*)(q + d0);
    av[0] += a4.x; av[1] += a4.y; av[2] += a4.z; av[3] += a4.w;
    smt += q[8];
  }
  float oinv = 1.f / smt;
  float ov4[4];
#pragma unroll
  for (int d = 0; d < 4; ++d) ov4[d] = av[d] * oinv;
  float lo[BOTT];
#pragma unroll
  for (int o = 0; o < BOTT; ++o) {
    float acc = 0.f;
#pragma unroll
    for (int jj = 0; jj < 4; ++jj) acc += ov4[jj] * out_lo_w[(j0 + jj) * BOTT + o];
    acc += __shfl_xor(acc, 1, 8); acc += __shfl_xor(acc, 2, 8); acc += __shfl_xor(acc, 4, 8);
    lo[o] = acc + out_lo_b[o];
  }
  float4 hin4 = *(const float4*)(h_in + (size_t)row * HIDD + j0);
  float pre[4] = {hin4.x, hin4.y, hin4.z, hin4.w};
#pragma unroll
  for (int jj = 0; jj < 4; ++jj) {
    float acc = out_hi_b[j0 + jj] + pre[jj];
#pragma unroll
    for (int o = 0; o < BOTT; ++o) acc += lo[o] * out_hi_w[o * HIDD + j0 + jj];
    pre[jj] = acc;
  }
  float h2[4];
  {
    float s1 = pre[0] + pre[1] + pre[2] + pre[3];
    float s2 = pre[0]*pre[0] + pre[1]*pre[1] + pre[2]*pre[2] + pre[3]*pre[3];
    s1 += __shfl_xor(s1, 1, 8); s1 += __shfl_xor(s1, 2, 8); s1 += __shfl_xor(s1, 4, 8);
    s2 += __shfl_xor(s2, 1, 8); s2 += __shfl_xor(s2, 2, 8); s2 += __shfl_xor(s2, 4, 8);
    float mean = s1 * (1.f / 32.f);
    float var = s2 * (1.f / 32.f) - mean * mean;
    float r = rsqrtf(var + 1e-5f);
#pragma unroll
    for (int jj = 0; jj < 4; ++jj)
      h2[jj] = (pre[jj] - mean) * r * at_g[j0 + jj] + at_b[j0 + jj];
  }
  float pl[BOTT];
#pragma unroll
  for (int o = 0; o < BOTT; ++o) {
    float acc = 0.f;
#pragma unroll
    for (int jj = 0; jj < 4; ++jj) acc += h2[jj] * pred_lo_w[(j0 + jj) * BOTT + o];
    acc += __shfl_xor(acc, 1, 8); acc += __shfl_xor(acc, 2, 8); acc += __shfl_xor(acc, 4, 8);
    pl[o] = acc + pred_lo_b[o];
  }
  float xm[BOTT];
  {
    float m = 0.f;
#pragma unroll
    for (int o = 0; o < BOTT; ++o) m += pl[o];
    m *= (1.f / BOTT);
    float var = 0.f;
#pragma unroll
    for (int o = 0; o < BOTT; ++o) { float d = pl[o] - m; var += d * d; }
    var *= (1.f / BOTT);
    float r = rsqrtf(var + 1e-5f);
#pragma unroll
    for (int o = 0; o < BOTT; ++o)
      xm[o] = fmaxf((pl[o] - m) * r * mid_g[o] + mid_b[o], 0.f);
  }
  float ga[BOTT];
#pragma unroll
  for (int o = 0; o < BOTT; ++o) {
    float acc = 0.f;
#pragma unroll
    for (int jj = 0; jj < 4; ++jj) acc += h2[jj] * gate_w1[(j0 + jj) * BOTT + o];
    acc += __shfl_xor(acc, 1, 8); acc += __shfl_xor(acc, 2, 8); acc += __shfl_xor(acc, 4, 8);
    ga[o] = fmaxf(acc + gate_b1[o], 0.f);
  }
  float xl = x[(size_t)b * TT * NN + (size_t)(TT - 1) * NN + n];
  float dec = __expf(log_decay[0]);
#pragma unroll
  for (int ii = 0; ii < 2; ++ii) {
    int i = l + ii * 8;
    if (i < HZNN) {
      float accp = pred_hi_b[i];
#pragma unroll
      for (int o = 0; o < BOTT; ++o) accp += xm[o] * pred_hi_w[o * HZNN + i];
      float accg = gate_b2[i];
#pragma unroll
      for (int o = 0; o < BOTT; ++o) accg += ga[o] * gate_w2[o * HZNN + i];
      float gt = 1.f / (1.f + __expf(-accg));
      float pr = xl * __expf(-dec * (float)(i + 1));
      out[(size_t)row * HZNN + i] = gt * accp + (1.f - gt) * pr;
    }
  }
}

extern "C" void kernel_launch(void* const* d_in, const int* in_sizes, int n_in,
                              void* d_out, int out_size, void* d_ws, size_t ws_size,
                              hipStream_t stream) {
  const float* x          = (const float*)d_in[0];
  const float* adj        = (const float*)d_in[1];
  const float* dw_w       = (const float*)d_in[2];
  const float* dw_b       = (const float*)d_in[3];
  const float* bn1_g      = (const float*)d_in[4];
  const float* bn1_b      = (const float*)d_in[5];
  const float* pw_w       = (const float*)d_in[6];
  const float* pw_b       = (const float*)d_in[7];
  const float* bn2_g      = (const float*)d_in[8];
  const float* bn2_b      = (const float*)d_in[9];
  const float* feat_w     = (const float*)d_in[10];
  const float* feat_b     = (const float*)d_in[11];
  const float* scale_w    = (const float*)d_in[12];
  const float* scale_b    = (const float*)d_in[13];
  const float* scale_ln_g = (const float*)d_in[14];
  const float* scale_ln_b = (const float*)d_in[15];
  const float* fusion_w   = (const float*)d_in[16];
  const float* fus_lo_w   = (const float*)d_in[17];
  const float* fus_lo_b   = (const float*)d_in[18];
  const float* fus_hi_w   = (const float*)d_in[19];
  const float* fus_hi_b   = (const float*)d_in[20];
  const float* sp_ln_g    = (const float*)d_in[21];
  const float* sp_ln_b    = (const float*)d_in[22];
  const float* qkv_lo_w   = (const float*)d_in[23];
  const float* qkv_lo_b   = (const float*)d_in[24];
  const float* qkv_hi_w   = (const float*)d_in[25];
  const float* qkv_hi_b   = (const float*)d_in[26];
  const float* graph_U    = (const float*)d_in[27];
  const float* graph_V    = (const float*)d_in[28];
  const float* adj_mix    = (const float*)d_in[29];
  const float* adj_scale  = (const float*)d_in[30];
  const float* out_lo_w   = (const float*)d_in[31];
  const float* out_lo_b   = (const float*)d_in[32];
  const float* out_hi_w   = (const float*)d_in[33];
  const float* out_hi_b   = (const float*)d_in[34];
  const float* at_ln_g    = (const float*)d_in[35];
  const float* at_ln_b    = (const float*)d_in[36];
  const float* pred_lo_w  = (const float*)d_in[37];
  const float* pred_lo_b  = (const float*)d_in[38];
  const float* mid_ln_g   = (const float*)d_in[39];
  const float* mid_ln_b   = (const float*)d_in[40];
  const float* pred_hi_w  = (const float*)d_in[41];
  const float* pred_hi_b  = (const float*)d_in[42];
  const float* log_decay  = (const float*)d_in[43];
  const float* gate_w1    = (const float*)d_in[44];
  const float* gate_b1    = (const float*)d_in[45];
  const float* gate_w2    = (const float*)d_in[46];
  const float* gate_b2    = (const float*)d_in[47];

  float* ws = (float*)d_ws;
  float* h0    = ws;                       // [N][256]
  float* g1    = h0 + (size_t)NN * BC;
  float* g2    = g1 + (size_t)NN * BC;
  float* g3    = g2 + (size_t)NN * BC;
  float* hfull = g3 + (size_t)NN * BC;     // [B*N][32]
  float* Qw    = hfull + (size_t)BB * NN * HIDD;
  float* Kw    = Qw + (size_t)BB * NN * HIDD;
  float* Vw    = Kw + (size_t)BB * NN * HIDD;
  float* VgT   = Vw + (size_t)BB * NN * HIDD;      // [N][8]
  float* sval  = VgT + (size_t)NN * 8;             // [N][CAP]
  float* sraw  = sval + (size_t)NN * CAP;          // [N][CAP]
  int*   sidx  = (int*)(sraw + (size_t)NN * CAP);  // [N][CAP]
  int*   scnt  = sidx + (size_t)NN * CAP;          // [N]
  float* P     = (float*)(scnt + NN + 3);          // [3][32][PROWS][12]
  P = (float*)(((uintptr_t)P + 15) & ~(uintptr_t)15);

  k_prep_temporal<<<NN + 47, 256, 0, stream>>>(
      adj, graph_V, sidx, sval, sraw, scnt, VgT,
      x, dw_w, dw_b, bn1_g, bn1_b, pw_w, pw_b, bn2_g, bn2_b, feat_w, feat_b, h0);
  k_spmm_sp<<<NN, 256, 0, stream>>>(sidx, sval, scnt, h0, g1);
  k_spmm_sp<<<NN, 256, 0, stream>>>(sidx, sval, scnt, g1, g2);
  k_spmm_sp<<<NN, 256, 0, stream>>>(sidx, sval, scnt, g2, g3);
  k_fuse_qkv<<<(BB * NN) / 16, 256, 0, stream>>>(
      h0, g1, g2, g3, scale_w, scale_b, scale_ln_g, scale_ln_b, fusion_w,
      fus_lo_w, fus_lo_b, fus_hi_w, fus_hi_b, sp_ln_g, sp_ln_b,
      qkv_lo_w, qkv_lo_b, qkv_hi_w, qkv_hi_b, hfull, Qw, Kw, Vw);
  k_attn<<<dim3(32, NTILES, MSPLIT + 1), 256, 0, stream>>>(
      Qw, Kw, Vw, graph_U, VgT, sidx, sraw, scnt, adj_mix, adj_scale, P);
  k_final<<<(BB * NN) / 32, 256, 0, stream>>>(
      P, hfull, x, out_lo_w, out_lo_b, out_hi_w, out_hi_b, at_ln_g, at_ln_b,
      pred_lo_w, pred_lo_b, mid_ln_g, mid_ln_b, pred_hi_w, pred_hi_b,
      log_decay, gate_w1, gate_b1, gate_w2, gate_b2, (float*)d_out);
}

// Round 8
// 255.573 us; speedup vs baseline: 1.1452x; 1.1452x over previous
//
#include <hip/hip_runtime.h>
#include <math.h>

#define NN 1500
#define BB 8
#define TT 32
#define HIDD 32
#define BOTT 8
#define CC 16
#define NHEADS 4
#define NSCALES 4
#define HZNN 12
#define BC (BB*HIDD)   // 256 columns for diffusion SPMM
#define CAP 128        // max nnz per adjacency row (mean ~16)
#define MC 128         // attention K/V chunk rows staged in LDS
#define PROWS 1536     // padded row count (24 tiles x 64)
#define KS_STRIDE 24   // LDS K' row stride in halfs (48B: 16B-aligned, 2-way banks)
#define VS_STRIDE 136  // LDS V^T row stride in halfs (272B: 16B-aligned, 2-way banks)

typedef _Float16 f16;
typedef __attribute__((ext_vector_type(4))) _Float16 half4;
typedef __attribute__((ext_vector_type(4))) float floatx4;

// ---------------- fused: prep (blocks 0..NN-1) + temporal (blocks NN..) ----------------
__global__ void k_prep_temporal(const float* __restrict__ adj,
                                const float* __restrict__ gV,
                                int* __restrict__ sidx, float* __restrict__ sval,
                                float* __restrict__ sraw, int* __restrict__ scnt,
                                float* __restrict__ VgT,
                                f16* __restrict__ Qh, f16* __restrict__ Kh,
                                f16* __restrict__ VT,
                                const float* __restrict__ x,
    const float* __restrict__ dw_w, const float* __restrict__ dw_b,
    const float* __restrict__ bn1_g, const float* __restrict__ bn1_b,
    const float* __restrict__ pw_w, const float* __restrict__ pw_b,
    const float* __restrict__ bn2_g, const float* __restrict__ bn2_b,
    const float* __restrict__ feat_w, const float* __restrict__ feat_b,
    float* __restrict__ h0) {
  if (blockIdx.x < NN) {
    int n = blockIdx.x;
    int tid = threadIdx.x;
    const float* row = adj + (size_t)n * NN;
    __shared__ int cnt;
    __shared__ float red[4];
    __shared__ float s_inv;
    float ssum = 0.f;
    for (int m = tid; m < NN; m += 256) ssum += row[m];
    for (int off = 32; off > 0; off >>= 1) ssum += __shfl_down(ssum, off, 64);
    if ((tid & 63) == 0) red[tid >> 6] = ssum;
    if (tid == 0) cnt = 0;
    __syncthreads();
    if (tid == 0) {
      float tot = red[0] + red[1] + red[2] + red[3] + 1.0f;
      s_inv = 1.0f / (tot + 1e-8f);
    }
    __syncthreads();
    float inv = s_inv;
    for (int m = tid; m < NN; m += 256) {
      float a = row[m];
      if (a != 0.f || m == n) {
        int pos = atomicAdd(&cnt, 1);
        if (pos < CAP) {
          sidx[n * CAP + pos] = m;
          sval[n * CAP + pos] = (a + (m == n ? 1.f : 0.f)) * inv;
          sraw[n * CAP + pos] = a;
        }
      }
    }
    __syncthreads();
    if (tid == 0) scnt[n] = min(cnt, CAP);
    if (n == 0) {
      for (int m = tid; m < NN; m += 256) {
#pragma unroll
        for (int j = 0; j < 8; ++j) VgT[m * 8 + j] = gV[j * NN + m];
      }
    }
    if (n == 2) {
      // zero Qh/Kh pad rows 1500..1535 (all 32 bh)
      for (int idx = tid; idx < 32 * 36 * 16; idx += 256) {
        int bb = idx / (36 * 16), rem = idx % (36 * 16);
        size_t off = ((size_t)bb * PROWS + NN + rem / 16) * 16 + (rem % 16);
        Qh[off] = (f16)0.f;
        Kh[off] = (f16)0.f;
      }
      // V^T ones row (d=8): 1 for m<NN (denominator trick), 0 at pads
      for (int idx = tid; idx < 32 * PROWS; idx += 256) {
        int bb = idx / PROWS, m = idx % PROWS;
        VT[((size_t)bb * 16 + 8) * PROWS + m] = (f16)((m < NN) ? 1.f : 0.f);
      }
      // V^T pad cols for d=0..7
      for (int idx = tid; idx < 32 * 8 * 36; idx += 256) {
        int bb = idx / (8 * 36), rem = idx % (8 * 36);
        VT[((size_t)bb * 16 + rem / 36) * PROWS + NN + (rem % 36)] = (f16)0.f;
      }
    }
  } else {
    int tid = (blockIdx.x - NN) * 256 + threadIdx.x;
    if (tid >= BB * NN) return;
    int b = tid / NN, n = tid % NN;
    float s[TT];
#pragma unroll
    for (int t = 0; t < TT; ++t) s[t] = x[(size_t)b * TT * NN + (size_t)t * NN + n];
    float w0 = dw_w[0], w1 = dw_w[1], w2 = dw_w[2];
    float db = dw_b[0], g1v = bn1_g[0], b1v = bn1_b[0];
    float dwr[TT];
#pragma unroll
    for (int t = 0; t < TT; ++t) {
      float left  = (t > 0)      ? s[t - 1] : 0.f;
      float right = (t < TT - 1) ? s[t + 1] : 0.f;
      float v = left * w0 + s[t] * w1 + right * w2;
      v = (v + db) * g1v + b1v;
      dwr[t] = fmaxf(v, 0.f);
    }
    float mo[CC];
#pragma unroll
    for (int o = 0; o < CC; ++o) mo[o] = 0.f;
    for (int t = 0; t < TT; ++t) {
      float d = dwr[t];
#pragma unroll
      for (int o = 0; o < CC; ++o) {
        float v = (d * pw_w[o] + pw_b[o]) * bn2_g[o] + bn2_b[o];
        mo[o] += fmaxf(v, 0.f);
      }
    }
#pragma unroll
    for (int o = 0; o < CC; ++o) mo[o] *= (1.f / TT);
    float* dst = h0 + (size_t)n * BC + b * HIDD;
    for (int j = 0; j < HIDD; ++j) {
      float acc = feat_b[j];
#pragma unroll
      for (int o = 0; o < CC; ++o) acc += mo[o] * feat_w[o * HIDD + j];
      dst[j] = acc;
    }
  }
}

// ---------------- sparse diffusion: Y[n,:] = sum_e val_e * X[idx_e,:] ----------------
__global__ void k_spmm_sp(const int* __restrict__ sidx, const float* __restrict__ sval,
                          const int* __restrict__ scnt,
                          const float* __restrict__ X, float* __restrict__ Y) {
  int n = blockIdx.x;
  int tid = threadIdx.x;
  __shared__ int   li[CAP];
  __shared__ float lv[CAP];
  int cnt = scnt[n];
  if (tid < cnt) { li[tid] = sidx[n * CAP + tid]; lv[tid] = sval[n * CAP + tid]; }
  __syncthreads();
  float acc = 0.f;
  for (int e = 0; e < cnt; ++e) acc += lv[e] * X[(size_t)li[e] * BC + tid];
  Y[(size_t)n * BC + tid] = acc;
}

// ---------------- multi-scale fusion + sp_ln + qkv: 16 lanes per row ----------------
// Also emits f16 MFMA operand buffers: Qh=[q*scl|U], Kh=[k|Vg], VT=V^T.
__global__ void k_fuse_qkv(
    const float* __restrict__ h0, const float* __restrict__ g1,
    const float* __restrict__ g2, const float* __restrict__ g3,
    const float* __restrict__ scale_w, const float* __restrict__ scale_b,
    const float* __restrict__ sln_g, const float* __restrict__ sln_b,
    const float* __restrict__ fusion_w,
    const float* __restrict__ fus_lo_w, const float* __restrict__ fus_lo_b,
    const float* __restrict__ fus_hi_w, const float* __restrict__ fus_hi_b,
    const float* __restrict__ sp_g, const float* __restrict__ sp_b,
    const float* __restrict__ qkv_lo_w, const float* __restrict__ qkv_lo_b,
    const float* __restrict__ qkv_hi_w, const float* __restrict__ qkv_hi_b,
    const float* __restrict__ gU, const float* __restrict__ VgT,
    float* __restrict__ h_out,
    float* __restrict__ Qw, float* __restrict__ Kw, float* __restrict__ Vw,
    f16* __restrict__ Qh, f16* __restrict__ Kh, f16* __restrict__ VT) {
  int tid = threadIdx.x;
  int gr = tid >> 4, l = tid & 15;
  int row = blockIdx.x * 16 + gr;          // 750 blocks * 16 rows = 12000
  int b = row / NN, n = row % NN;
  size_t rofs = (size_t)n * BC + b * HIDD;
  int j0 = 2 * l;
  float fw0 = fusion_w[0], fw1 = fusion_w[1], fw2 = fusion_w[2], fw3 = fusion_w[3];
  float fm = fmaxf(fmaxf(fw0, fw1), fmaxf(fw2, fw3));
  float e0 = __expf(fw0 - fm), e1 = __expf(fw1 - fm), e2 = __expf(fw2 - fm), e3 = __expf(fw3 - fm);
  float einv = 1.f / (e0 + e1 + e2 + e3);
  float alpha[4] = {e0 * einv, e1 * einv, e2 * einv, e3 * einv};
  const float* srcp[4] = {h0, g1, g2, g3};
  float fused[2] = {0.f, 0.f};
#pragma unroll
  for (int i = 0; i < NSCALES; ++i) {
    const float* sp = srcp[i] + rofs;
    float src[32];
#pragma unroll
    for (int k4 = 0; k4 < 8; ++k4) {
      float4 f = *(const float4*)(sp + k4 * 4);
      src[k4 * 4] = f.x; src[k4 * 4 + 1] = f.y; src[k4 * 4 + 2] = f.z; src[k4 * 4 + 3] = f.w;
    }
    const float* W = scale_w + i * HIDD * HIDD;
    float t0 = scale_b[i * HIDD + j0], t1v = scale_b[i * HIDD + j0 + 1];
#pragma unroll
    for (int k = 0; k < 32; ++k) {
      float2 w = *(const float2*)(W + k * HIDD + j0);
      t0 += src[k] * w.x; t1v += src[k] * w.y;
    }
    float s1 = t0 + t1v;
    float s2 = t0 * t0 + t1v * t1v;
    s1 += __shfl_xor(s1, 1, 16); s1 += __shfl_xor(s1, 2, 16);
    s1 += __shfl_xor(s1, 4, 16); s1 += __shfl_xor(s1, 8, 16);
    s2 += __shfl_xor(s2, 1, 16); s2 += __shfl_xor(s2, 2, 16);
    s2 += __shfl_xor(s2, 4, 16); s2 += __shfl_xor(s2, 8, 16);
    float mean = s1 * (1.f / 32.f);
    float var = s2 * (1.f / 32.f) - mean * mean;
    float r = rsqrtf(var + 1e-5f);
    float a = alpha[i];
    float tn0 = (t0 - mean) * r * sln_g[i * HIDD + j0] + sln_b[i * HIDD + j0];
    float tn1 = (t1v - mean) * r * sln_g[i * HIDD + j0 + 1] + sln_b[i * HIDD + j0 + 1];
    fused[0] += a * fmaxf(tn0, 0.f);
    fused[1] += a * fmaxf(tn1, 0.f);
  }
  float lo[BOTT];
#pragma unroll
  for (int o = 0; o < BOTT; ++o) {
    float acc = fused[0] * fus_lo_w[j0 * BOTT + o] + fused[1] * fus_lo_w[(j0 + 1) * BOTT + o];
    acc += __shfl_xor(acc, 1, 16); acc += __shfl_xor(acc, 2, 16);
    acc += __shfl_xor(acc, 4, 16); acc += __shfl_xor(acc, 8, 16);
    lo[o] = acc + fus_lo_b[o];
  }
  float2 hv2 = *(const float2*)(h0 + rofs + j0);
  float pre[2] = {hv2.x, hv2.y};
#pragma unroll
  for (int jj = 0; jj < 2; ++jj) {
    float acc = fus_hi_b[j0 + jj] + pre[jj];
#pragma unroll
    for (int o = 0; o < BOTT; ++o) acc += lo[o] * fus_hi_w[o * HIDD + j0 + jj];
    pre[jj] = acc;
  }
  {
    float s1 = pre[0] + pre[1];
    float s2 = pre[0] * pre[0] + pre[1] * pre[1];
    s1 += __shfl_xor(s1, 1, 16); s1 += __shfl_xor(s1, 2, 16);
    s1 += __shfl_xor(s1, 4, 16); s1 += __shfl_xor(s1, 8, 16);
    s2 += __shfl_xor(s2, 1, 16); s2 += __shfl_xor(s2, 2, 16);
    s2 += __shfl_xor(s2, 4, 16); s2 += __shfl_xor(s2, 8, 16);
    float mean = s1 * (1.f / 32.f);
    float var = s2 * (1.f / 32.f) - mean * mean;
    float r = rsqrtf(var + 1e-5f);
#pragma unroll
    for (int jj = 0; jj < 2; ++jj)
      pre[jj] = (pre[jj] - mean) * r * sp_g[j0 + jj] + sp_b[j0 + jj];
  }
  *(float2*)(h_out + (size_t)row * HIDD + j0) = make_float2(pre[0], pre[1]);
  float t1[24];
#pragma unroll
  for (int o = 0; o < 24; ++o) {
    float acc = pre[0] * qkv_lo_w[j0 * 24 + o] + pre[1] * qkv_lo_w[(j0 + 1) * 24 + o];
    acc += __shfl_xor(acc, 1, 16); acc += __shfl_xor(acc, 2, 16);
    acc += __shfl_xor(acc, 4, 16); acc += __shfl_xor(acc, 8, 16);
    t1[o] = acc + qkv_lo_b[o];
  }
  const float scl = 0.35355339059327373f;  // 1/sqrt(8)
  int sub = l >> 3, d = l & 7;
#pragma unroll
  for (int part = 0; part < 3; ++part) {
    float* dst = (part == 0) ? Qw : (part == 1) ? Kw : Vw;
#pragma unroll
    for (int hh = 0; hh < 2; ++hh) {
      int hd = sub * 2 + hh;
      int p = part * 32 + hd * 8 + d;
      float acc = qkv_hi_b[p];
#pragma unroll
      for (int o = 0; o < 24; ++o) acc += t1[o] * qkv_hi_w[o * 96 + p];
      dst[(((size_t)b * NHEADS + hd) * NN + n) * 8 + d] = acc;
      int bh = b * NHEADS + hd;
      if (part == 0) {
        Qh[((size_t)bh * PROWS + n) * 16 + d] = (f16)(acc * scl);
        Qh[((size_t)bh * PROWS + n) * 16 + 8 + d] = (f16)gU[n * 8 + d];
      } else if (part == 1) {
        Kh[((size_t)bh * PROWS + n) * 16 + d] = (f16)acc;
        Kh[((size_t)bh * PROWS + n) * 16 + 8 + d] = (f16)VgT[n * 8 + d];
      } else {
        VT[((size_t)bh * 16 + d) * PROWS + n] = (f16)acc;
      }
    }
  }
}

// ---------------- dense attention via MFMA 16x16x16 f16 ----------------
// S^T = K'·Q'^T so exp(S) C-layout == A-layout of the PV mfma (no LDS transpose).
// Vext col 8 = ones -> O col 8 = softmax denominator for free.
// Padded rows (1500..1535): K'=0, Vext=0 -> exp(0)*0 = 0 contribution.
__global__ void __launch_bounds__(256, 4)
k_attn_mfma(const f16* __restrict__ Qh, const f16* __restrict__ Kh,
            const f16* __restrict__ VT, float* __restrict__ P) {
  int bh = blockIdx.x;
  int tile = blockIdx.y;        // 24 tiles x 64 rows
  int tid = threadIdx.x;
  int wave = tid >> 6, lane = tid & 63;
  int quad = lane >> 4, l16 = lane & 15;
  __shared__ f16 Ks[MC * KS_STRIDE];   // 6 KB
  __shared__ f16 Vs[16 * VS_STRIDE];   // 4.3 KB
  int n0 = tile * 64 + wave * 16;
  // Q' B-frag (loop-invariant): B[k=quad*4+j][col=n=l16]
  half4 qf = *(const half4*)(Qh + ((size_t)bh * PROWS + n0 + l16) * 16 + quad * 4);
  floatx4 acc = {0.f, 0.f, 0.f, 0.f};
  for (int m0 = 0; m0 < PROWS; m0 += MC) {
    __syncthreads();
    {
      int row = tid >> 1, h = (tid & 1) * 8;
      *(float4*)(Ks + row * KS_STRIDE + h) =
          *(const float4*)(Kh + ((size_t)bh * PROWS + m0 + row) * 16 + h);
      int d = tid >> 4, c = (tid & 15) * 8;
      *(float4*)(Vs + d * VS_STRIDE + c) =
          *(const float4*)(VT + ((size_t)bh * 16 + d) * PROWS + m0 + c);
    }
    __syncthreads();
#pragma unroll
    for (int mt = 0; mt < MC / 16; ++mt) {
      // K' A-frag: A[row=m=l16][k=quad*4+j]
      half4 kf = *(const half4*)(Ks + (mt * 16 + l16) * KS_STRIDE + quad * 4);
      floatx4 s = __builtin_amdgcn_mfma_f32_16x16x16f16(
          kf, qf, (floatx4){0.f, 0.f, 0.f, 0.f}, 0, 0, 0);
      // s[r] = S[n=l16][m = m0+mt*16+quad*4+r]
      half4 pf;
      pf[0] = (f16)__expf(s[0]);
      pf[1] = (f16)__expf(s[1]);
      pf[2] = (f16)__expf(s[2]);
      pf[3] = (f16)__expf(s[3]);
      // Vext B-frag: B[k=m=quad*4+j][col=d=l16] from V^T rows
      half4 vf = *(const half4*)(Vs + l16 * VS_STRIDE + mt * 16 + quad * 4);
      acc = __builtin_amdgcn_mfma_f32_16x16x16f16(pf, vf, acc, 0, 0, 0);
    }
  }
  // acc[r] = O[n = n0+quad*4+r][d = l16]; d=8 is the row sum
  if (l16 < 9) {
#pragma unroll
    for (int r = 0; r < 4; ++r) {
      int n = n0 + quad * 4 + r;
      P[((size_t)bh * PROWS + n) * 12 + l16] = acc[r];
    }
  }
}

// ---------------- sparse adjacency correction -> partial slot 1 ----------------
__global__ void k_attn_sp(const float* __restrict__ Qw, const float* __restrict__ Kw,
                          const float* __restrict__ Vw,
                          const float* __restrict__ gU, const float* __restrict__ VgT,
                          const int* __restrict__ sidx, const float* __restrict__ sraw,
                          const int* __restrict__ scnt,
                          const float* __restrict__ adj_mix, const float* __restrict__ adj_scale,
                          float* __restrict__ P) {
  int bh = blockIdx.x;
  int tid = threadIdx.x;
  int g = tid >> 3, p = tid & 7;
  float smix = adj_scale[0] / (1.f + __expf(-adj_mix[0]));
  const float scl = 0.35355339059327373f;
  const float* Kb = Kw + (size_t)bh * NN * 8;
  const float* Vb = Vw + (size_t)bh * NN * 8;
  for (int rr = 0; rr < 4; ++rr) {
    int n = blockIdx.y * 128 + g * 4 + rr;
    float acc[8] = {0.f, 0.f, 0.f, 0.f, 0.f, 0.f, 0.f, 0.f};
    float sm = 0.f;
    if (n < NN) {
      const float* qp = Qw + ((size_t)bh * NN + n) * 8;
      const float* up = gU + n * 8;
      float qv[16];
#pragma unroll
      for (int d = 0; d < 8; ++d) { qv[d] = qp[d] * scl; qv[8 + d] = up[d]; }
      int cnt = scnt[n];
      for (int e = p; e < cnt; e += 8) {
        int m = sidx[n * CAP + e];
        float a = sraw[n * CAP + e];
        if (a != 0.f) {
          const float* kp = Kb + (size_t)m * 8;
          float4 k0 = *(const float4*)(kp);
          float4 k1 = *(const float4*)(kp + 4);
          const float* gp = VgT + (size_t)m * 8;
          float4 k2 = *(const float4*)(gp);
          float4 k3 = *(const float4*)(gp + 4);
          float s = qv[0]*k0.x + qv[1]*k0.y + qv[2]*k0.z + qv[3]*k0.w
                  + qv[4]*k1.x + qv[5]*k1.y + qv[6]*k1.z + qv[7]*k1.w
                  + qv[8]*k2.x + qv[9]*k2.y + qv[10]*k2.z + qv[11]*k2.w
                  + qv[12]*k3.x + qv[13]*k3.y + qv[14]*k3.z + qv[15]*k3.w;
          float ep = __expf(s);
          float dlt = ep * (__expf(smix * a) - 1.f);
          sm += dlt;
          const float* vp = Vb + (size_t)m * 8;
          float4 v0 = *(const float4*)(vp);
          float4 v1 = *(const float4*)(vp + 4);
          acc[0] += dlt * v0.x; acc[1] += dlt * v0.y; acc[2] += dlt * v0.z; acc[3] += dlt * v0.w;
          acc[4] += dlt * v1.x; acc[5] += dlt * v1.y; acc[6] += dlt * v1.z; acc[7] += dlt * v1.w;
        }
      }
    }
    sm += __shfl_xor(sm, 1, 8); sm += __shfl_xor(sm, 2, 8); sm += __shfl_xor(sm, 4, 8);
#pragma unroll
    for (int d = 0; d < 8; ++d) {
      acc[d] += __shfl_xor(acc[d], 1, 8);
      acc[d] += __shfl_xor(acc[d], 2, 8);
      acc[d] += __shfl_xor(acc[d], 4, 8);
    }
    float val = acc[0];
#pragma unroll
    for (int d = 1; d < 8; ++d) if (p == d) val = acc[d];
    if (n < NN) {
      float* dst = P + ((size_t)(32 + bh) * PROWS + n) * 12;
      dst[p] = val;
      if (p == 0) dst[8] = sm;
    }
  }
}

// ---------------- merge partials + output proj + at_ln + gated predictor: 8 lanes/row ----
__global__ void k_final(const float* __restrict__ P, const float* __restrict__ h_in,
    const float* __restrict__ x,
    const float* __restrict__ out_lo_w, const float* __restrict__ out_lo_b,
    const float* __restrict__ out_hi_w, const float* __restrict__ out_hi_b,
    const float* __restrict__ at_g, const float* __restrict__ at_b,
    const float* __restrict__ pred_lo_w, const float* __restrict__ pred_lo_b,
    const float* __restrict__ mid_g, const float* __restrict__ mid_b,
    const float* __restrict__ pred_hi_w, const float* __restrict__ pred_hi_b,
    const float* __restrict__ log_decay,
    const float* __restrict__ gate_w1, const float* __restrict__ gate_b1,
    const float* __restrict__ gate_w2, const float* __restrict__ gate_b2,
    float* __restrict__ out) {
  int tid = threadIdx.x;
  int gr = tid >> 3, l = tid & 7;
  int row = blockIdx.x * 32 + gr;   // 375 blocks * 32 rows = 12000
  int b = row / NN, n = row % NN;
  int j0 = 4 * l;
  int hd = l >> 1, d0 = (l & 1) * 4;
  int bh = b * NHEADS + hd;
  float av[4] = {0.f, 0.f, 0.f, 0.f};
  float smt = 0.f;
#pragma unroll
  for (int z = 0; z < 2; ++z) {
    const float* q = P + ((size_t)(z * 32 + bh) * PROWS + n) * 12;
    float4 a4 = *(const float4*)(q + d0);
    av[0] += a4.x; av[1] += a4.y; av[2] += a4.z; av[3] += a4.w;
    smt += q[8];
  }
  float oinv = 1.f / smt;
  float ov4[4];
#pragma unroll
  for (int d = 0; d < 4; ++d) ov4[d] = av[d] * oinv;
  float lo[BOTT];
#pragma unroll
  for (int o = 0; o < BOTT; ++o) {
    float acc = 0.f;
#pragma unroll
    for (int jj = 0; jj < 4; ++jj) acc += ov4[jj] * out_lo_w[(j0 + jj) * BOTT + o];
    acc += __shfl_xor(acc, 1, 8); acc += __shfl_xor(acc, 2, 8); acc += __shfl_xor(acc, 4, 8);
    lo[o] = acc + out_lo_b[o];
  }
  float4 hin4 = *(const float4*)(h_in + (size_t)row * HIDD + j0);
  float pre[4] = {hin4.x, hin4.y, hin4.z, hin4.w};
#pragma unroll
  for (int jj = 0; jj < 4; ++jj) {
    float acc = out_hi_b[j0 + jj] + pre[jj];
#pragma unroll
    for (int o = 0; o < BOTT; ++o) acc += lo[o] * out_hi_w[o * HIDD + j0 + jj];
    pre[jj] = acc;
  }
  float h2[4];
  {
    float s1 = pre[0] + pre[1] + pre[2] + pre[3];
    float s2 = pre[0]*pre[0] + pre[1]*pre[1] + pre[2]*pre[2] + pre[3]*pre[3];
    s1 += __shfl_xor(s1, 1, 8); s1 += __shfl_xor(s1, 2, 8); s1 += __shfl_xor(s1, 4, 8);
    s2 += __shfl_xor(s2, 1, 8); s2 += __shfl_xor(s2, 2, 8); s2 += __shfl_xor(s2, 4, 8);
    float mean = s1 * (1.f / 32.f);
    float var = s2 * (1.f / 32.f) - mean * mean;
    float r = rsqrtf(var + 1e-5f);
#pragma unroll
    for (int jj = 0; jj < 4; ++jj)
      h2[jj] = (pre[jj] - mean) * r * at_g[j0 + jj] + at_b[j0 + jj];
  }
  float pl[BOTT];
#pragma unroll
  for (int o = 0; o < BOTT; ++o) {
    float acc = 0.f;
#pragma unroll
    for (int jj = 0; jj < 4; ++jj) acc += h2[jj] * pred_lo_w[(j0 + jj) * BOTT + o];
    acc += __shfl_xor(acc, 1, 8); acc += __shfl_xor(acc, 2, 8); acc += __shfl_xor(acc, 4, 8);
    pl[o] = acc + pred_lo_b[o];
  }
  float xm[BOTT];
  {
    float m = 0.f;
#pragma unroll
    for (int o = 0; o < BOTT; ++o) m += pl[o];
    m *= (1.f / BOTT);
    float var = 0.f;
#pragma unroll
    for (int o = 0; o < BOTT; ++o) { float d = pl[o] - m; var += d * d; }
    var *= (1.f / BOTT);
    float r = rsqrtf(var + 1e-5f);
#pragma unroll
    for (int o = 0; o < BOTT; ++o)
      xm[o] = fmaxf((pl[o] - m) * r * mid_g[o] + mid_b[o], 0.f);
  }
  float ga[BOTT];
#pragma unroll
  for (int o = 0; o < BOTT; ++o) {
    float acc = 0.f;
#pragma unroll
    for (int jj = 0; jj < 4; ++jj) acc += h2[jj] * gate_w1[(j0 + jj) * BOTT + o];
    acc += __shfl_xor(acc, 1, 8); acc += __shfl_xor(acc, 2, 8); acc += __shfl_xor(acc, 4, 8);
    ga[o] = fmaxf(acc + gate_b1[o], 0.f);
  }
  float xl = x[(size_t)b * TT * NN + (size_t)(TT - 1) * NN + n];
  float dec = __expf(log_decay[0]);
#pragma unroll
  for (int ii = 0; ii < 2; ++ii) {
    int i = l + ii * 8;
    if (i < HZNN) {
      float accp = pred_hi_b[i];
#pragma unroll
      for (int o = 0; o < BOTT; ++o) accp += xm[o] * pred_hi_w[o * HZNN + i];
      float accg = gate_b2[i];
#pragma unroll
      for (int o = 0; o < BOTT; ++o) accg += ga[o] * gate_w2[o * HZNN + i];
      float gt = 1.f / (1.f + __expf(-accg));
      float pr = xl * __expf(-dec * (float)(i + 1));
      out[(size_t)row * HZNN + i] = gt * accp + (1.f - gt) * pr;
    }
  }
}

extern "C" void kernel_launch(void* const* d_in, const int* in_sizes, int n_in,
                              void* d_out, int out_size, void* d_ws, size_t ws_size,
                              hipStream_t stream) {
  const float* x          = (const float*)d_in[0];
  const float* adj        = (const float*)d_in[1];
  const float* dw_w       = (const float*)d_in[2];
  const float* dw_b       = (const float*)d_in[3];
  const float* bn1_g      = (const float*)d_in[4];
  const float* bn1_b      = (const float*)d_in[5];
  const float* pw_w       = (const float*)d_in[6];
  const float* pw_b       = (const float*)d_in[7];
  const float* bn2_g      = (const float*)d_in[8];
  const float* bn2_b      = (const float*)d_in[9];
  const float* feat_w     = (const float*)d_in[10];
  const float* feat_b     = (const float*)d_in[11];
  const float* scale_w    = (const float*)d_in[12];
  const float* scale_b    = (const float*)d_in[13];
  const float* scale_ln_g = (const float*)d_in[14];
  const float* scale_ln_b = (const float*)d_in[15];
  const float* fusion_w   = (const float*)d_in[16];
  const float* fus_lo_w   = (const float*)d_in[17];
  const float* fus_lo_b   = (const float*)d_in[18];
  const float* fus_hi_w   = (const float*)d_in[19];
  const float* fus_hi_b   = (const float*)d_in[20];
  const float* sp_ln_g    = (const float*)d_in[21];
  const float* sp_ln_b    = (const float*)d_in[22];
  const float* qkv_lo_w   = (const float*)d_in[23];
  const float* qkv_lo_b   = (const float*)d_in[24];
  const float* qkv_hi_w   = (const float*)d_in[25];
  const float* qkv_hi_b   = (const float*)d_in[26];
  const float* graph_U    = (const float*)d_in[27];
  const float* graph_V    = (const float*)d_in[28];
  const float* adj_mix    = (const float*)d_in[29];
  const float* adj_scale  = (const float*)d_in[30];
  const float* out_lo_w   = (const float*)d_in[31];
  const float* out_lo_b   = (const float*)d_in[32];
  const float* out_hi_w   = (const float*)d_in[33];
  const float* out_hi_b   = (const float*)d_in[34];
  const float* at_ln_g    = (const float*)d_in[35];
  const float* at_ln_b    = (const float*)d_in[36];
  const float* pred_lo_w  = (const float*)d_in[37];
  const float* pred_lo_b  = (const float*)d_in[38];
  const float* mid_ln_g   = (const float*)d_in[39];
  const float* mid_ln_b   = (const float*)d_in[40];
  const float* pred_hi_w  = (const float*)d_in[41];
  const float* pred_hi_b  = (const float*)d_in[42];
  const float* log_decay  = (const float*)d_in[43];
  const float* gate_w1    = (const float*)d_in[44];
  const float* gate_b1    = (const float*)d_in[45];
  const float* gate_w2    = (const float*)d_in[46];
  const float* gate_b2    = (const float*)d_in[47];

  float* ws = (float*)d_ws;
  float* h0    = ws;                       // [N][256]
  float* g1    = h0 + (size_t)NN * BC;
  float* g2    = g1 + (size_t)NN * BC;
  float* g3    = g2 + (size_t)NN * BC;
  float* hfull = g3 + (size_t)NN * BC;     // [B*N][32]
  float* Qw    = hfull + (size_t)BB * NN * HIDD;
  float* Kw    = Qw + (size_t)BB * NN * HIDD;
  float* Vw    = Kw + (size_t)BB * NN * HIDD;
  float* VgT   = Vw + (size_t)BB * NN * HIDD;      // [N][8]
  float* sval  = VgT + (size_t)NN * 8;             // [N][CAP]
  float* sraw  = sval + (size_t)NN * CAP;          // [N][CAP]
  int*   sidx  = (int*)(sraw + (size_t)NN * CAP);  // [N][CAP]
  int*   scnt  = sidx + (size_t)NN * CAP;          // [N]
  float* P     = (float*)(scnt + NN + 3);          // [2][32][PROWS][12]
  P = (float*)(((uintptr_t)P + 15) & ~(uintptr_t)15);
  f16* Qh = (f16*)(P + (size_t)2 * 32 * PROWS * 12);   // [32][PROWS][16]
  f16* Kh = Qh + (size_t)32 * PROWS * 16;              // [32][PROWS][16]
  f16* VT = Kh + (size_t)32 * PROWS * 16;              // [32][16][PROWS]

  k_prep_temporal<<<NN + 47, 256, 0, stream>>>(
      adj, graph_V, sidx, sval, sraw, scnt, VgT, Qh, Kh, VT,
      x, dw_w, dw_b, bn1_g, bn1_b, pw_w, pw_b, bn2_g, bn2_b, feat_w, feat_b, h0);
  k_spmm_sp<<<NN, 256, 0, stream>>>(sidx, sval, scnt, h0, g1);
  k_spmm_sp<<<NN, 256, 0, stream>>>(sidx, sval, scnt, g1, g2);
  k_spmm_sp<<<NN, 256, 0, stream>>>(sidx, sval, scnt, g2, g3);
  k_fuse_qkv<<<(BB * NN) / 16, 256, 0, stream>>>(
      h0, g1, g2, g3, scale_w, scale_b, scale_ln_g, scale_ln_b, fusion_w,
      fus_lo_w, fus_lo_b, fus_hi_w, fus_hi_b, sp_ln_g, sp_ln_b,
      qkv_lo_w, qkv_lo_b, qkv_hi_w, qkv_hi_b, graph_U, VgT,
      hfull, Qw, Kw, Vw, Qh, Kh, VT);
  k_attn_mfma<<<dim3(32, PROWS / 64), 256, 0, stream>>>(Qh, Kh, VT, P);
  k_attn_sp<<<dim3(32, 12), 256, 0, stream>>>(
      Qw, Kw, Vw, graph_U, VgT, sidx, sraw, scnt, adj_mix, adj_scale, P);
  k_final<<<(BB * NN) / 32, 256, 0, stream>>>(
      P, hfull, x, out_lo_w, out_lo_b, out_hi_w, out_hi_b, at_ln_g, at_ln_b,
      pred_lo_w, pred_lo_b, mid_ln_g, mid_ln_b, pred_hi_w, pred_hi_b,
      log_decay, gate_w1, gate_b1, gate_w2, gate_b2, (float*)d_out);
}

// Round 9
// 254.952 us; speedup vs baseline: 1.1480x; 1.0024x over previous
//
#include <hip/hip_runtime.h>
#include <math.h>

#define NN 1500
#define BB 8
#define TT 32
#define HIDD 32
#define BOTT 8
#define CC 16
#define NHEADS 4
#define NSCALES 4
#define HZNN 12
#define BC (BB*HIDD)   // 256 columns for diffusion SPMM
#define CAP 128        // max nnz per adjacency row (mean ~16)
#define MC 128         // attention K/V chunk rows staged in LDS
#define PROWS 1536     // padded row count (24 tiles x 64)
#define KS_STRIDE 24   // LDS K' row stride in halfs
#define VS_STRIDE 136  // LDS V^T row stride in halfs

typedef _Float16 f16;
typedef __attribute__((ext_vector_type(4))) _Float16 half4;
typedef __attribute__((ext_vector_type(4))) float floatx4;

// ---------------- fused: prep (blocks 0..NN-1) + temporal (blocks NN..) ----------------
__global__ void k_prep_temporal(const float* __restrict__ adj,
                                const float* __restrict__ gV,
                                int* __restrict__ sidx, float* __restrict__ sval,
                                float* __restrict__ sraw, int* __restrict__ scnt,
                                float* __restrict__ VgT,
                                f16* __restrict__ Qh, f16* __restrict__ Kh,
                                f16* __restrict__ VT,
                                const float* __restrict__ x,
    const float* __restrict__ dw_w, const float* __restrict__ dw_b,
    const float* __restrict__ bn1_g, const float* __restrict__ bn1_b,
    const float* __restrict__ pw_w, const float* __restrict__ pw_b,
    const float* __restrict__ bn2_g, const float* __restrict__ bn2_b,
    const float* __restrict__ feat_w, const float* __restrict__ feat_b,
    float* __restrict__ h0) {
  if (blockIdx.x < NN) {
    int n = blockIdx.x;
    int tid = threadIdx.x;
    const float* row = adj + (size_t)n * NN;
    __shared__ int cnt;
    __shared__ float red[4];
    __shared__ float s_inv;
    float ssum = 0.f;
    for (int m = tid; m < NN; m += 256) ssum += row[m];
    for (int off = 32; off > 0; off >>= 1) ssum += __shfl_down(ssum, off, 64);
    if ((tid & 63) == 0) red[tid >> 6] = ssum;
    if (tid == 0) cnt = 0;
    __syncthreads();
    if (tid == 0) {
      float tot = red[0] + red[1] + red[2] + red[3] + 1.0f;
      s_inv = 1.0f / (tot + 1e-8f);
    }
    __syncthreads();
    float inv = s_inv;
    for (int m = tid; m < NN; m += 256) {
      float a = row[m];
      if (a != 0.f || m == n) {
        int pos = atomicAdd(&cnt, 1);
        if (pos < CAP) {
          sidx[n * CAP + pos] = m;
          sval[n * CAP + pos] = (a + (m == n ? 1.f : 0.f)) * inv;
          sraw[n * CAP + pos] = a;
        }
      }
    }
    __syncthreads();
    if (tid == 0) scnt[n] = min(cnt, CAP);
    if (n == 0) {
      for (int m = tid; m < NN; m += 256) {
#pragma unroll
        for (int j = 0; j < 8; ++j) VgT[m * 8 + j] = gV[j * NN + m];
      }
    }
    if (n == 2) {
      // zero Qh/Kh pad rows 1500..1535 (all 32 bh)
      for (int idx = tid; idx < 32 * 36 * 16; idx += 256) {
        int bb = idx / (36 * 16), rem = idx % (36 * 16);
        size_t off = ((size_t)bb * PROWS + NN + rem / 16) * 16 + (rem % 16);
        Qh[off] = (f16)0.f;
        Kh[off] = (f16)0.f;
      }
      // V^T ones row (d=8): 1 for m<NN (denominator trick), 0 at pads
      for (int idx = tid; idx < 32 * PROWS; idx += 256) {
        int bb = idx / PROWS, m = idx % PROWS;
        VT[((size_t)bb * 16 + 8) * PROWS + m] = (f16)((m < NN) ? 1.f : 0.f);
      }
      // V^T pad cols for d=0..7
      for (int idx = tid; idx < 32 * 8 * 36; idx += 256) {
        int bb = idx / (8 * 36), rem = idx % (8 * 36);
        VT[((size_t)bb * 16 + rem / 36) * PROWS + NN + (rem % 36)] = (f16)0.f;
      }
    }
  } else {
    int tid = (blockIdx.x - NN) * 256 + threadIdx.x;
    if (tid >= BB * NN) return;
    int b = tid / NN, n = tid % NN;
    float s[TT];
#pragma unroll
    for (int t = 0; t < TT; ++t) s[t] = x[(size_t)b * TT * NN + (size_t)t * NN + n];
    float w0 = dw_w[0], w1 = dw_w[1], w2 = dw_w[2];
    float db = dw_b[0], g1v = bn1_g[0], b1v = bn1_b[0];
    float dwr[TT];
#pragma unroll
    for (int t = 0; t < TT; ++t) {
      float left  = (t > 0)      ? s[t - 1] : 0.f;
      float right = (t < TT - 1) ? s[t + 1] : 0.f;
      float v = left * w0 + s[t] * w1 + right * w2;
      v = (v + db) * g1v + b1v;
      dwr[t] = fmaxf(v, 0.f);
    }
    float mo[CC];
#pragma unroll
    for (int o = 0; o < CC; ++o) mo[o] = 0.f;
    for (int t = 0; t < TT; ++t) {
      float d = dwr[t];
#pragma unroll
      for (int o = 0; o < CC; ++o) {
        float v = (d * pw_w[o] + pw_b[o]) * bn2_g[o] + bn2_b[o];
        mo[o] += fmaxf(v, 0.f);
      }
    }
#pragma unroll
    for (int o = 0; o < CC; ++o) mo[o] *= (1.f / TT);
    float* dst = h0 + (size_t)n * BC + b * HIDD;
    for (int j = 0; j < HIDD; ++j) {
      float acc = feat_b[j];
#pragma unroll
      for (int o = 0; o < CC; ++o) acc += mo[o] * feat_w[o * HIDD + j];
      dst[j] = acc;
    }
  }
}

// ---------------- sparse diffusion: Y[n,:] = sum_e val_e * X[idx_e,:] ----------------
// Edge-list reads are wave-uniform (same address all lanes) -> L1 broadcast;
// no LDS staging, no barriers.
__global__ void k_spmm_sp(const int* __restrict__ sidx, const float* __restrict__ sval,
                          const int* __restrict__ scnt,
                          const float* __restrict__ X, float* __restrict__ Y) {
  int n = blockIdx.x;
  int tid = threadIdx.x;
  int cnt = scnt[n];
  const int* ip = sidx + n * CAP;
  const float* vp = sval + n * CAP;
  float acc = 0.f;
  for (int e = 0; e < cnt; ++e) acc += vp[e] * X[(size_t)ip[e] * BC + tid];
  Y[(size_t)n * BC + tid] = acc;
}

// ---------------- multi-scale fusion + sp_ln + qkv: 16 lanes per row ----------------
// Emits only f16 MFMA operand buffers: Qh=[q*scl|U], Kh=[k|Vg], VT=V^T.
__global__ void k_fuse_qkv(
    const float* __restrict__ h0, const float* __restrict__ g1,
    const float* __restrict__ g2, const float* __restrict__ g3,
    const float* __restrict__ scale_w, const float* __restrict__ scale_b,
    const float* __restrict__ sln_g, const float* __restrict__ sln_b,
    const float* __restrict__ fusion_w,
    const float* __restrict__ fus_lo_w, const float* __restrict__ fus_lo_b,
    const float* __restrict__ fus_hi_w, const float* __restrict__ fus_hi_b,
    const float* __restrict__ sp_g, const float* __restrict__ sp_b,
    const float* __restrict__ qkv_lo_w, const float* __restrict__ qkv_lo_b,
    const float* __restrict__ qkv_hi_w, const float* __restrict__ qkv_hi_b,
    const float* __restrict__ gU, const float* __restrict__ VgT,
    float* __restrict__ h_out,
    f16* __restrict__ Qh, f16* __restrict__ Kh, f16* __restrict__ VT) {
  int tid = threadIdx.x;
  int gr = tid >> 4, l = tid & 15;
  int row = blockIdx.x * 16 + gr;          // 750 blocks * 16 rows = 12000
  int b = row / NN, n = row % NN;
  size_t rofs = (size_t)n * BC + b * HIDD;
  int j0 = 2 * l;
  float fw0 = fusion_w[0], fw1 = fusion_w[1], fw2 = fusion_w[2], fw3 = fusion_w[3];
  float fm = fmaxf(fmaxf(fw0, fw1), fmaxf(fw2, fw3));
  float e0 = __expf(fw0 - fm), e1 = __expf(fw1 - fm), e2 = __expf(fw2 - fm), e3 = __expf(fw3 - fm);
  float einv = 1.f / (e0 + e1 + e2 + e3);
  float alpha[4] = {e0 * einv, e1 * einv, e2 * einv, e3 * einv};
  const float* srcp[4] = {h0, g1, g2, g3};
  float fused[2] = {0.f, 0.f};
#pragma unroll
  for (int i = 0; i < NSCALES; ++i) {
    const float* sp = srcp[i] + rofs;
    float src[32];
#pragma unroll
    for (int k4 = 0; k4 < 8; ++k4) {
      float4 f = *(const float4*)(sp + k4 * 4);
      src[k4 * 4] = f.x; src[k4 * 4 + 1] = f.y; src[k4 * 4 + 2] = f.z; src[k4 * 4 + 3] = f.w;
    }
    const float* W = scale_w + i * HIDD * HIDD;
    float t0 = scale_b[i * HIDD + j0], t1v = scale_b[i * HIDD + j0 + 1];
#pragma unroll
    for (int k = 0; k < 32; ++k) {
      float2 w = *(const float2*)(W + k * HIDD + j0);
      t0 += src[k] * w.x; t1v += src[k] * w.y;
    }
    float s1 = t0 + t1v;
    float s2 = t0 * t0 + t1v * t1v;
    s1 += __shfl_xor(s1, 1, 16); s1 += __shfl_xor(s1, 2, 16);
    s1 += __shfl_xor(s1, 4, 16); s1 += __shfl_xor(s1, 8, 16);
    s2 += __shfl_xor(s2, 1, 16); s2 += __shfl_xor(s2, 2, 16);
    s2 += __shfl_xor(s2, 4, 16); s2 += __shfl_xor(s2, 8, 16);
    float mean = s1 * (1.f / 32.f);
    float var = s2 * (1.f / 32.f) - mean * mean;
    float r = rsqrtf(var + 1e-5f);
    float a = alpha[i];
    float tn0 = (t0 - mean) * r * sln_g[i * HIDD + j0] + sln_b[i * HIDD + j0];
    float tn1 = (t1v - mean) * r * sln_g[i * HIDD + j0 + 1] + sln_b[i * HIDD + j0 + 1];
    fused[0] += a * fmaxf(tn0, 0.f);
    fused[1] += a * fmaxf(tn1, 0.f);
  }
  float lo[BOTT];
#pragma unroll
  for (int o = 0; o < BOTT; ++o) {
    float acc = fused[0] * fus_lo_w[j0 * BOTT + o] + fused[1] * fus_lo_w[(j0 + 1) * BOTT + o];
    acc += __shfl_xor(acc, 1, 16); acc += __shfl_xor(acc, 2, 16);
    acc += __shfl_xor(acc, 4, 16); acc += __shfl_xor(acc, 8, 16);
    lo[o] = acc + fus_lo_b[o];
  }
  float2 hv2 = *(const float2*)(h0 + rofs + j0);
  float pre[2] = {hv2.x, hv2.y};
#pragma unroll
  for (int jj = 0; jj < 2; ++jj) {
    float acc = fus_hi_b[j0 + jj] + pre[jj];
#pragma unroll
    for (int o = 0; o < BOTT; ++o) acc += lo[o] * fus_hi_w[o * HIDD + j0 + jj];
    pre[jj] = acc;
  }
  {
    float s1 = pre[0] + pre[1];
    float s2 = pre[0] * pre[0] + pre[1] * pre[1];
    s1 += __shfl_xor(s1, 1, 16); s1 += __shfl_xor(s1, 2, 16);
    s1 += __shfl_xor(s1, 4, 16); s1 += __shfl_xor(s1, 8, 16);
    s2 += __shfl_xor(s2, 1, 16); s2 += __shfl_xor(s2, 2, 16);
    s2 += __shfl_xor(s2, 4, 16); s2 += __shfl_xor(s2, 8, 16);
    float mean = s1 * (1.f / 32.f);
    float var = s2 * (1.f / 32.f) - mean * mean;
    float r = rsqrtf(var + 1e-5f);
#pragma unroll
    for (int jj = 0; jj < 2; ++jj)
      pre[jj] = (pre[jj] - mean) * r * sp_g[j0 + jj] + sp_b[j0 + jj];
  }
  *(float2*)(h_out + (size_t)row * HIDD + j0) = make_float2(pre[0], pre[1]);
  float t1[24];
#pragma unroll
  for (int o = 0; o < 24; ++o) {
    float acc = pre[0] * qkv_lo_w[j0 * 24 + o] + pre[1] * qkv_lo_w[(j0 + 1) * 24 + o];
    acc += __shfl_xor(acc, 1, 16); acc += __shfl_xor(acc, 2, 16);
    acc += __shfl_xor(acc, 4, 16); acc += __shfl_xor(acc, 8, 16);
    t1[o] = acc + qkv_lo_b[o];
  }
  const float scl = 0.35355339059327373f;  // 1/sqrt(8)
  int sub = l >> 3, d = l & 7;
#pragma unroll
  for (int part = 0; part < 3; ++part) {
#pragma unroll
    for (int hh = 0; hh < 2; ++hh) {
      int hd = sub * 2 + hh;
      int p = part * 32 + hd * 8 + d;
      float acc = qkv_hi_b[p];
#pragma unroll
      for (int o = 0; o < 24; ++o) acc += t1[o] * qkv_hi_w[o * 96 + p];
      int bh = b * NHEADS + hd;
      if (part == 0) {
        Qh[((size_t)bh * PROWS + n) * 16 + d] = (f16)(acc * scl);
        Qh[((size_t)bh * PROWS + n) * 16 + 8 + d] = (f16)gU[n * 8 + d];
      } else if (part == 1) {
        Kh[((size_t)bh * PROWS + n) * 16 + d] = (f16)acc;
        Kh[((size_t)bh * PROWS + n) * 16 + 8 + d] = (f16)VgT[n * 8 + d];
      } else {
        VT[((size_t)bh * 16 + d) * PROWS + n] = (f16)acc;
      }
    }
  }
}

// ---------------- attention: dense MFMA tiles (y<24) + sparse adj correction (y>=24) ----
// Dense: S^T = K'·Q'^T so exp(S) C-layout == A-layout of the PV mfma; Vext col 8 = ones
// -> O col 8 = softmax denominator. Sparse: e_true = e'*exp(smix*a) delta over adj nnz,
// computed from the SAME f16-rounded operands (error cancels in the merge).
__global__ void __launch_bounds__(256, 4)
k_attn(const f16* __restrict__ Qh, const f16* __restrict__ Kh,
       const f16* __restrict__ VT,
       const int* __restrict__ sidx, const float* __restrict__ sraw,
       const int* __restrict__ scnt,
       const float* __restrict__ adj_mix, const float* __restrict__ adj_scale,
       float* __restrict__ P) {
  int bh = blockIdx.x;
  int tid = threadIdx.x;
  __shared__ f16 Ks[MC * KS_STRIDE];   // 6 KB
  __shared__ f16 Vs[16 * VS_STRIDE];   // 4.3 KB
  if (blockIdx.y < 24) {
    int tile = blockIdx.y;
    int wave = tid >> 6, lane = tid & 63;
    int quad = lane >> 4, l16 = lane & 15;
    int n0 = tile * 64 + wave * 16;
    half4 qf = *(const half4*)(Qh + ((size_t)bh * PROWS + n0 + l16) * 16 + quad * 4);
    floatx4 acc = {0.f, 0.f, 0.f, 0.f};
    for (int m0 = 0; m0 < PROWS; m0 += MC) {
      __syncthreads();
      {
        int row = tid >> 1, h = (tid & 1) * 8;
        *(float4*)(Ks + row * KS_STRIDE + h) =
            *(const float4*)(Kh + ((size_t)bh * PROWS + m0 + row) * 16 + h);
        int d = tid >> 4, c = (tid & 15) * 8;
        *(float4*)(Vs + d * VS_STRIDE + c) =
            *(const float4*)(VT + ((size_t)bh * 16 + d) * PROWS + m0 + c);
      }
      __syncthreads();
#pragma unroll
      for (int mt = 0; mt < MC / 16; ++mt) {
        half4 kf = *(const half4*)(Ks + (mt * 16 + l16) * KS_STRIDE + quad * 4);
        floatx4 s = __builtin_amdgcn_mfma_f32_16x16x16f16(
            kf, qf, (floatx4){0.f, 0.f, 0.f, 0.f}, 0, 0, 0);
        half4 pf;
        pf[0] = (f16)__expf(s[0]);
        pf[1] = (f16)__expf(s[1]);
        pf[2] = (f16)__expf(s[2]);
        pf[3] = (f16)__expf(s[3]);
        half4 vf = *(const half4*)(Vs + l16 * VS_STRIDE + mt * 16 + quad * 4);
        acc = __builtin_amdgcn_mfma_f32_16x16x16f16(pf, vf, acc, 0, 0, 0);
      }
    }
    if (l16 < 9) {
#pragma unroll
      for (int r = 0; r < 4; ++r) {
        int n = n0 + quad * 4 + r;
        P[((size_t)bh * PROWS + n) * 12 + l16] = acc[r];
      }
    }
  } else {
    // sparse adjacency correction -> partial slot 1
    int ytile = blockIdx.y - 24;
    int g = tid >> 3, p = tid & 7;
    float smix = adj_scale[0] / (1.f + __expf(-adj_mix[0]));
    for (int rr = 0; rr < 4; ++rr) {
      int n = ytile * 128 + g * 4 + rr;
      float acc[8] = {0.f, 0.f, 0.f, 0.f, 0.f, 0.f, 0.f, 0.f};
      float sm = 0.f;
      if (n < NN) {
        const f16* qp = Qh + ((size_t)bh * PROWS + n) * 16;
        float qv[16];
#pragma unroll
        for (int d = 0; d < 16; ++d) qv[d] = (float)qp[d];  // already *scl and |U
        int cnt = scnt[n];
        for (int e = p; e < cnt; e += 8) {
          int m = sidx[n * CAP + e];
          float a = sraw[n * CAP + e];
          if (a != 0.f) {
            const f16* kp = Kh + ((size_t)bh * PROWS + m) * 16;
            float s = 0.f;
#pragma unroll
            for (int d = 0; d < 16; ++d) s += qv[d] * (float)kp[d];
            float ep = __expf(s);
            float dlt = ep * (__expf(smix * a) - 1.f);
            sm += dlt;
#pragma unroll
            for (int d = 0; d < 8; ++d)
              acc[d] += dlt * (float)VT[((size_t)bh * 16 + d) * PROWS + m];
          }
        }
      }
      sm += __shfl_xor(sm, 1, 8); sm += __shfl_xor(sm, 2, 8); sm += __shfl_xor(sm, 4, 8);
#pragma unroll
      for (int d = 0; d < 8; ++d) {
        acc[d] += __shfl_xor(acc[d], 1, 8);
        acc[d] += __shfl_xor(acc[d], 2, 8);
        acc[d] += __shfl_xor(acc[d], 4, 8);
      }
      float val = acc[0];
#pragma unroll
      for (int d = 1; d < 8; ++d) if (p == d) val = acc[d];
      if (n < NN) {
        float* dst = P + ((size_t)(32 + bh) * PROWS + n) * 12;
        dst[p] = val;
        if (p == 0) dst[8] = sm;
      }
    }
  }
}

// ---------------- merge partials + output proj + at_ln + gated predictor: 8 lanes/row ----
__global__ void k_final(const float* __restrict__ P, const float* __restrict__ h_in,
    const float* __restrict__ x,
    const float* __restrict__ out_lo_w, const float* __restrict__ out_lo_b,
    const float* __restrict__ out_hi_w, const float* __restrict__ out_hi_b,
    const float* __restrict__ at_g, const float* __restrict__ at_b,
    const float* __restrict__ pred_lo_w, const float* __restrict__ pred_lo_b,
    const float* __restrict__ mid_g, const float* __restrict__ mid_b,
    const float* __restrict__ pred_hi_w, const float* __restrict__ pred_hi_b,
    const float* __restrict__ log_decay,
    const float* __restrict__ gate_w1, const float* __restrict__ gate_b1,
    const float* __restrict__ gate_w2, const float* __restrict__ gate_b2,
    float* __restrict__ out) {
  int tid = threadIdx.x;
  int gr = tid >> 3, l = tid & 7;
  int row = blockIdx.x * 32 + gr;   // 375 blocks * 32 rows = 12000
  int b = row / NN, n = row % NN;
  int j0 = 4 * l;
  int hd = l >> 1, d0 = (l & 1) * 4;
  int bh = b * NHEADS + hd;
  float av[4] = {0.f, 0.f, 0.f, 0.f};
  float smt = 0.f;
#pragma unroll
  for (int z = 0; z < 2; ++z) {
    const float* q = P + ((size_t)(z * 32 + bh) * PROWS + n) * 12;
    float4 a4 = *(const float4*)(q + d0);
    av[0] += a4.x; av[1] += a4.y; av[2] += a4.z; av[3] += a4.w;
    smt += q[8];
  }
  float oinv = 1.f / smt;
  float ov4[4];
#pragma unroll
  for (int d = 0; d < 4; ++d) ov4[d] = av[d] * oinv;
  float lo[BOTT];
#pragma unroll
  for (int o = 0; o < BOTT; ++o) {
    float acc = 0.f;
#pragma unroll
    for (int jj = 0; jj < 4; ++jj) acc += ov4[jj] * out_lo_w[(j0 + jj) * BOTT + o];
    acc += __shfl_xor(acc, 1, 8); acc += __shfl_xor(acc, 2, 8); acc += __shfl_xor(acc, 4, 8);
    lo[o] = acc + out_lo_b[o];
  }
  float4 hin4 = *(const float4*)(h_in + (size_t)row * HIDD + j0);
  float pre[4] = {hin4.x, hin4.y, hin4.z, hin4.w};
#pragma unroll
  for (int jj = 0; jj < 4; ++jj) {
    float acc = out_hi_b[j0 + jj] + pre[jj];
#pragma unroll
    for (int o = 0; o < BOTT; ++o) acc += lo[o] * out_hi_w[o * HIDD + j0 + jj];
    pre[jj] = acc;
  }
  float h2[4];
  {
    float s1 = pre[0] + pre[1] + pre[2] + pre[3];
    float s2 = pre[0]*pre[0] + pre[1]*pre[1] + pre[2]*pre[2] + pre[3]*pre[3];
    s1 += __shfl_xor(s1, 1, 8); s1 += __shfl_xor(s1, 2, 8); s1 += __shfl_xor(s1, 4, 8);
    s2 += __shfl_xor(s2, 1, 8); s2 += __shfl_xor(s2, 2, 8); s2 += __shfl_xor(s2, 4, 8);
    float mean = s1 * (1.f / 32.f);
    float var = s2 * (1.f / 32.f) - mean * mean;
    float r = rsqrtf(var + 1e-5f);
#pragma unroll
    for (int jj = 0; jj < 4; ++jj)
      h2[jj] = (pre[jj] - mean) * r * at_g[j0 + jj] + at_b[j0 + jj];
  }
  float pl[BOTT];
#pragma unroll
  for (int o = 0; o < BOTT; ++o) {
    float acc = 0.f;
#pragma unroll
    for (int jj = 0; jj < 4; ++jj) acc += h2[jj] * pred_lo_w[(j0 + jj) * BOTT + o];
    acc += __shfl_xor(acc, 1, 8); acc += __shfl_xor(acc, 2, 8); acc += __shfl_xor(acc, 4, 8);
    pl[o] = acc + pred_lo_b[o];
  }
  float xm[BOTT];
  {
    float m = 0.f;
#pragma unroll
    for (int o = 0; o < BOTT; ++o) m += pl[o];
    m *= (1.f / BOTT);
    float var = 0.f;
#pragma unroll
    for (int o = 0; o < BOTT; ++o) { float d = pl[o] - m; var += d * d; }
    var *= (1.f / BOTT);
    float r = rsqrtf(var + 1e-5f);
#pragma unroll
    for (int o = 0; o < BOTT; ++o)
      xm[o] = fmaxf((pl[o] - m) * r * mid_g[o] + mid_b[o], 0.f);
  }
  float ga[BOTT];
#pragma unroll
  for (int o = 0; o < BOTT; ++o) {
    float acc = 0.f;
#pragma unroll
    for (int jj = 0; jj < 4; ++jj) acc += h2[jj] * gate_w1[(j0 + jj) * BOTT + o];
    acc += __shfl_xor(acc, 1, 8); acc += __shfl_xor(acc, 2, 8); acc += __shfl_xor(acc, 4, 8);
    ga[o] = fmaxf(acc + gate_b1[o], 0.f);
  }
  float xl = x[(size_t)b * TT * NN + (size_t)(TT - 1) * NN + n];
  float dec = __expf(log_decay[0]);
#pragma unroll
  for (int ii = 0; ii < 2; ++ii) {
    int i = l + ii * 8;
    if (i < HZNN) {
      float accp = pred_hi_b[i];
#pragma unroll
      for (int o = 0; o < BOTT; ++o) accp += xm[o] * pred_hi_w[o * HZNN + i];
      float accg = gate_b2[i];
#pragma unroll
      for (int o = 0; o < BOTT; ++o) accg += ga[o] * gate_w2[o * HZNN + i];
      float gt = 1.f / (1.f + __expf(-accg));
      float pr = xl * __expf(-dec * (float)(i + 1));
      out[(size_t)row * HZNN + i] = gt * accp + (1.f - gt) * pr;
    }
  }
}

extern "C" void kernel_launch(void* const* d_in, const int* in_sizes, int n_in,
                              void* d_out, int out_size, void* d_ws, size_t ws_size,
                              hipStream_t stream) {
  const float* x          = (const float*)d_in[0];
  const float* adj        = (const float*)d_in[1];
  const float* dw_w       = (const float*)d_in[2];
  const float* dw_b       = (const float*)d_in[3];
  const float* bn1_g      = (const float*)d_in[4];
  const float* bn1_b      = (const float*)d_in[5];
  const float* pw_w       = (const float*)d_in[6];
  const float* pw_b       = (const float*)d_in[7];
  const float* bn2_g      = (const float*)d_in[8];
  const float* bn2_b      = (const float*)d_in[9];
  const float* feat_w     = (const float*)d_in[10];
  const float* feat_b     = (const float*)d_in[11];
  const float* scale_w    = (const float*)d_in[12];
  const float* scale_b    = (const float*)d_in[13];
  const float* scale_ln_g = (const float*)d_in[14];
  const float* scale_ln_b = (const float*)d_in[15];
  const float* fusion_w   = (const float*)d_in[16];
  const float* fus_lo_w   = (const float*)d_in[17];
  const float* fus_lo_b   = (const float*)d_in[18];
  const float* fus_hi_w   = (const float*)d_in[19];
  const float* fus_hi_b   = (const float*)d_in[20];
  const float* sp_ln_g    = (const float*)d_in[21];
  const float* sp_ln_b    = (const float*)d_in[22];
  const float* qkv_lo_w   = (const float*)d_in[23];
  const float* qkv_lo_b   = (const float*)d_in[24];
  const float* qkv_hi_w   = (const float*)d_in[25];
  const float* qkv_hi_b   = (const float*)d_in[26];
  const float* graph_U    = (const float*)d_in[27];
  const float* graph_V    = (const float*)d_in[28];
  const float* adj_mix    = (const float*)d_in[29];
  const float* adj_scale  = (const float*)d_in[30];
  const float* out_lo_w   = (const float*)d_in[31];
  const float* out_lo_b   = (const float*)d_in[32];
  const float* out_hi_w   = (const float*)d_in[33];
  const float* out_hi_b   = (const float*)d_in[34];
  const float* at_ln_g    = (const float*)d_in[35];
  const float* at_ln_b    = (const float*)d_in[36];
  const float* pred_lo_w  = (const float*)d_in[37];
  const float* pred_lo_b  = (const float*)d_in[38];
  const float* mid_ln_g   = (const float*)d_in[39];
  const float* mid_ln_b   = (const float*)d_in[40];
  const float* pred_hi_w  = (const float*)d_in[41];
  const float* pred_hi_b  = (const float*)d_in[42];
  const float* log_decay  = (const float*)d_in[43];
  const float* gate_w1    = (const float*)d_in[44];
  const float* gate_b1    = (const float*)d_in[45];
  const float* gate_w2    = (const float*)d_in[46];
  const float* gate_b2    = (const float*)d_in[47];

  float* ws = (float*)d_ws;
  float* h0    = ws;                       // [N][256]
  float* g1    = h0 + (size_t)NN * BC;
  float* g2    = g1 + (size_t)NN * BC;
  float* g3    = g2 + (size_t)NN * BC;
  float* hfull = g3 + (size_t)NN * BC;     // [B*N][32]
  float* VgT   = hfull + (size_t)BB * NN * HIDD;   // [N][8]
  float* sval  = VgT + (size_t)NN * 8;             // [N][CAP]
  float* sraw  = sval + (size_t)NN * CAP;          // [N][CAP]
  int*   sidx  = (int*)(sraw + (size_t)NN * CAP);  // [N][CAP]
  int*   scnt  = sidx + (size_t)NN * CAP;          // [N]
  float* P     = (float*)(scnt + NN + 3);          // [2][32][PROWS][12]
  P = (float*)(((uintptr_t)P + 15) & ~(uintptr_t)15);
  f16* Qh = (f16*)(P + (size_t)2 * 32 * PROWS * 12);   // [32][PROWS][16]
  f16* Kh = Qh + (size_t)32 * PROWS * 16;              // [32][PROWS][16]
  f16* VT = Kh + (size_t)32 * PROWS * 16;              // [32][16][PROWS]

  k_prep_temporal<<<NN + 47, 256, 0, stream>>>(
      adj, graph_V, sidx, sval, sraw, scnt, VgT, Qh, Kh, VT,
      x, dw_w, dw_b, bn1_g, bn1_b, pw_w, pw_b, bn2_g, bn2_b, feat_w, feat_b, h0);
  k_spmm_sp<<<NN, 256, 0, stream>>>(sidx, sval, scnt, h0, g1);
  k_spmm_sp<<<NN, 256, 0, stream>>>(sidx, sval, scnt, g1, g2);
  k_spmm_sp<<<NN, 256, 0, stream>>>(sidx, sval, scnt, g2, g3);
  k_fuse_qkv<<<(BB * NN) / 16, 256, 0, stream>>>(
      h0, g1, g2, g3, scale_w, scale_b, scale_ln_g, scale_ln_b, fusion_w,
      fus_lo_w, fus_lo_b, fus_hi_w, fus_hi_b, sp_ln_g, sp_ln_b,
      qkv_lo_w, qkv_lo_b, qkv_hi_w, qkv_hi_b, graph_U, VgT,
      hfull, Qh, Kh, VT);
  k_attn<<<dim3(32, 36), 256, 0, stream>>>(
      Qh, Kh, VT, sidx, sraw, scnt, adj_mix, adj_scale, P);
  k_final<<<(BB * NN) / 32, 256, 0, stream>>>(
      P, hfull, x, out_lo_w, out_lo_b, out_hi_w, out_hi_b, at_ln_g, at_ln_b,
      pred_lo_w, pred_lo_b, mid_ln_g, mid_ln_b, pred_hi_w, pred_hi_b,
      log_decay, gate_w1, gate_b1, gate_w2, gate_b2, (float*)d_out);
}

// Round 10
// 253.732 us; speedup vs baseline: 1.1535x; 1.0048x over previous
//
#include <hip/hip_runtime.h>
#include <math.h>

#define NN 1500
#define BB 8
#define TT 32
#define HIDD 32
#define BOTT 8
#define CC 16
#define NHEADS 4
#define NSCALES 4
#define HZNN 12
#define BC (BB*HIDD)   // 256 columns for diffusion SPMM
#define CAP 128        // max nnz per adjacency row (mean ~16)
#define MC 128         // attention K/V chunk rows staged in LDS
#define PROWS 1536     // padded row count (24 tiles x 64)
#define KS_STRIDE 24   // LDS K' row stride in halfs
#define VS_STRIDE 136  // LDS V^T row stride in halfs

typedef _Float16 f16;
typedef __attribute__((ext_vector_type(4))) _Float16 half4;
typedef __attribute__((ext_vector_type(4))) float floatx4;

// ---------------- fused: prep (blocks 0..NN-1) + temporal (blocks NN..) ----------------
__global__ void k_prep_temporal(const float* __restrict__ adj,
                                const float* __restrict__ gV,
                                int* __restrict__ sidx, float* __restrict__ sval,
                                float* __restrict__ sraw, int* __restrict__ scnt,
                                float* __restrict__ VgT,
                                f16* __restrict__ Qh, f16* __restrict__ Kh,
                                f16* __restrict__ VT, f16* __restrict__ Vh,
                                const float* __restrict__ x,
    const float* __restrict__ dw_w, const float* __restrict__ dw_b,
    const float* __restrict__ bn1_g, const float* __restrict__ bn1_b,
    const float* __restrict__ pw_w, const float* __restrict__ pw_b,
    const float* __restrict__ bn2_g, const float* __restrict__ bn2_b,
    const float* __restrict__ feat_w, const float* __restrict__ feat_b,
    float* __restrict__ h0) {
  if (blockIdx.x < NN) {
    int n = blockIdx.x;
    int tid = threadIdx.x;
    const float* row = adj + (size_t)n * NN;
    __shared__ int cnt;
    __shared__ float red[4];
    __shared__ float s_inv;
    float ssum = 0.f;
    for (int m = tid; m < NN; m += 256) ssum += row[m];
    for (int off = 32; off > 0; off >>= 1) ssum += __shfl_down(ssum, off, 64);
    if ((tid & 63) == 0) red[tid >> 6] = ssum;
    if (tid == 0) cnt = 0;
    __syncthreads();
    if (tid == 0) {
      float tot = red[0] + red[1] + red[2] + red[3] + 1.0f;
      s_inv = 1.0f / (tot + 1e-8f);
    }
    __syncthreads();
    float inv = s_inv;
    for (int m = tid; m < NN; m += 256) {
      float a = row[m];
      if (a != 0.f || m == n) {
        int pos = atomicAdd(&cnt, 1);
        if (pos < CAP) {
          sidx[n * CAP + pos] = m;
          sval[n * CAP + pos] = (a + (m == n ? 1.f : 0.f)) * inv;
          sraw[n * CAP + pos] = a;
        }
      }
    }
    __syncthreads();
    if (tid == 0) scnt[n] = min(cnt, CAP);
    if (n == 0) {
      for (int m = tid; m < NN; m += 256) {
#pragma unroll
        for (int j = 0; j < 8; ++j) VgT[m * 8 + j] = gV[j * NN + m];
      }
    }
    if (n == 2) {
      // zero Qh/Kh/Vh pad rows 1500..1535 (all 32 bh)
      for (int idx = tid; idx < 32 * 36 * 16; idx += 256) {
        int bb = idx / (36 * 16), rem = idx % (36 * 16);
        size_t off = ((size_t)bb * PROWS + NN + rem / 16) * 16 + (rem % 16);
        Qh[off] = (f16)0.f;
        Kh[off] = (f16)0.f;
        if ((rem % 16) < 8)
          Vh[((size_t)bb * PROWS + NN + rem / 16) * 8 + (rem % 16)] = (f16)0.f;
      }
      // V^T ones row (d=8): 1 for m<NN (denominator trick), 0 at pads
      for (int idx = tid; idx < 32 * PROWS; idx += 256) {
        int bb = idx / PROWS, m = idx % PROWS;
        VT[((size_t)bb * 16 + 8) * PROWS + m] = (f16)((m < NN) ? 1.f : 0.f);
      }
      // V^T pad cols for d=0..7
      for (int idx = tid; idx < 32 * 8 * 36; idx += 256) {
        int bb = idx / (8 * 36), rem = idx % (8 * 36);
        VT[((size_t)bb * 16 + rem / 36) * PROWS + NN + (rem % 36)] = (f16)0.f;
      }
    }
  } else {
    int tid = (blockIdx.x - NN) * 256 + threadIdx.x;
    if (tid >= BB * NN) return;
    int b = tid / NN, n = tid % NN;
    float s[TT];
#pragma unroll
    for (int t = 0; t < TT; ++t) s[t] = x[(size_t)b * TT * NN + (size_t)t * NN + n];
    float w0 = dw_w[0], w1 = dw_w[1], w2 = dw_w[2];
    float db = dw_b[0], g1v = bn1_g[0], b1v = bn1_b[0];
    float dwr[TT];
#pragma unroll
    for (int t = 0; t < TT; ++t) {
      float left  = (t > 0)      ? s[t - 1] : 0.f;
      float right = (t < TT - 1) ? s[t + 1] : 0.f;
      float v = left * w0 + s[t] * w1 + right * w2;
      v = (v + db) * g1v + b1v;
      dwr[t] = fmaxf(v, 0.f);
    }
    float mo[CC];
#pragma unroll
    for (int o = 0; o < CC; ++o) mo[o] = 0.f;
    for (int t = 0; t < TT; ++t) {
      float d = dwr[t];
#pragma unroll
      for (int o = 0; o < CC; ++o) {
        float v = (d * pw_w[o] + pw_b[o]) * bn2_g[o] + bn2_b[o];
        mo[o] += fmaxf(v, 0.f);
      }
    }
#pragma unroll
    for (int o = 0; o < CC; ++o) mo[o] *= (1.f / TT);
    float* dst = h0 + (size_t)n * BC + b * HIDD;
    for (int j = 0; j < HIDD; ++j) {
      float acc = feat_b[j];
#pragma unroll
      for (int o = 0; o < CC; ++o) acc += mo[o] * feat_w[o * HIDD + j];
      dst[j] = acc;
    }
  }
}

// ---------------- sparse diffusion: Y[n,:] = sum_e val_e * X[idx_e,:] ----------------
__global__ void k_spmm_sp(const int* __restrict__ sidx, const float* __restrict__ sval,
                          const int* __restrict__ scnt,
                          const float* __restrict__ X, float* __restrict__ Y) {
  int n = blockIdx.x;
  int tid = threadIdx.x;
  int cnt = scnt[n];
  const int* ip = sidx + n * CAP;
  const float* vp = sval + n * CAP;
  float acc = 0.f;
  for (int e = 0; e < cnt; ++e) acc += vp[e] * X[(size_t)ip[e] * BC + tid];
  Y[(size_t)n * BC + tid] = acc;
}

// ---------------- multi-scale fusion + sp_ln + qkv: 16 lanes per row ----------------
__global__ void k_fuse_qkv(
    const float* __restrict__ h0, const float* __restrict__ g1,
    const float* __restrict__ g2, const float* __restrict__ g3,
    const float* __restrict__ scale_w, const float* __restrict__ scale_b,
    const float* __restrict__ sln_g, const float* __restrict__ sln_b,
    const float* __restrict__ fusion_w,
    const float* __restrict__ fus_lo_w, const float* __restrict__ fus_lo_b,
    const float* __restrict__ fus_hi_w, const float* __restrict__ fus_hi_b,
    const float* __restrict__ sp_g, const float* __restrict__ sp_b,
    const float* __restrict__ qkv_lo_w, const float* __restrict__ qkv_lo_b,
    const float* __restrict__ qkv_hi_w, const float* __restrict__ qkv_hi_b,
    const float* __restrict__ gU, const float* __restrict__ VgT,
    float* __restrict__ h_out,
    f16* __restrict__ Qh, f16* __restrict__ Kh, f16* __restrict__ VT,
    f16* __restrict__ Vh) {
  int tid = threadIdx.x;
  int gr = tid >> 4, l = tid & 15;
  int row = blockIdx.x * 16 + gr;          // 750 blocks * 16 rows = 12000
  int b = row / NN, n = row % NN;
  size_t rofs = (size_t)n * BC + b * HIDD;
  int j0 = 2 * l;
  float fw0 = fusion_w[0], fw1 = fusion_w[1], fw2 = fusion_w[2], fw3 = fusion_w[3];
  float fm = fmaxf(fmaxf(fw0, fw1), fmaxf(fw2, fw3));
  float e0 = __expf(fw0 - fm), e1 = __expf(fw1 - fm), e2 = __expf(fw2 - fm), e3 = __expf(fw3 - fm);
  float einv = 1.f / (e0 + e1 + e2 + e3);
  float alpha[4] = {e0 * einv, e1 * einv, e2 * einv, e3 * einv};
  const float* srcp[4] = {h0, g1, g2, g3};
  float fused[2] = {0.f, 0.f};
#pragma unroll
  for (int i = 0; i < NSCALES; ++i) {
    const float* sp = srcp[i] + rofs;
    float src[32];
#pragma unroll
    for (int k4 = 0; k4 < 8; ++k4) {
      float4 f = *(const float4*)(sp + k4 * 4);
      src[k4 * 4] = f.x; src[k4 * 4 + 1] = f.y; src[k4 * 4 + 2] = f.z; src[k4 * 4 + 3] = f.w;
    }
    const float* W = scale_w + i * HIDD * HIDD;
    float t0 = scale_b[i * HIDD + j0], t1v = scale_b[i * HIDD + j0 + 1];
#pragma unroll
    for (int k = 0; k < 32; ++k) {
      float2 w = *(const float2*)(W + k * HIDD + j0);
      t0 += src[k] * w.x; t1v += src[k] * w.y;
    }
    float s1 = t0 + t1v;
    float s2 = t0 * t0 + t1v * t1v;
    s1 += __shfl_xor(s1, 1, 16); s1 += __shfl_xor(s1, 2, 16);
    s1 += __shfl_xor(s1, 4, 16); s1 += __shfl_xor(s1, 8, 16);
    s2 += __shfl_xor(s2, 1, 16); s2 += __shfl_xor(s2, 2, 16);
    s2 += __shfl_xor(s2, 4, 16); s2 += __shfl_xor(s2, 8, 16);
    float mean = s1 * (1.f / 32.f);
    float var = s2 * (1.f / 32.f) - mean * mean;
    float r = rsqrtf(var + 1e-5f);
    float a = alpha[i];
    float tn0 = (t0 - mean) * r * sln_g[i * HIDD + j0] + sln_b[i * HIDD + j0];
    float tn1 = (t1v - mean) * r * sln_g[i * HIDD + j0 + 1] + sln_b[i * HIDD + j0 + 1];
    fused[0] += a * fmaxf(tn0, 0.f);
    fused[1] += a * fmaxf(tn1, 0.f);
  }
  float lo[BOTT];
#pragma unroll
  for (int o = 0; o < BOTT; ++o) {
    float acc = fused[0] * fus_lo_w[j0 * BOTT + o] + fused[1] * fus_lo_w[(j0 + 1) * BOTT + o];
    acc += __shfl_xor(acc, 1, 16); acc += __shfl_xor(acc, 2, 16);
    acc += __shfl_xor(acc, 4, 16); acc += __shfl_xor(acc, 8, 16);
    lo[o] = acc + fus_lo_b[o];
  }
  float2 hv2 = *(const float2*)(h0 + rofs + j0);
  float pre[2] = {hv2.x, hv2.y};
#pragma unroll
  for (int jj = 0; jj < 2; ++jj) {
    float acc = fus_hi_b[j0 + jj] + pre[jj];
#pragma unroll
    for (int o = 0; o < BOTT; ++o) acc += lo[o] * fus_hi_w[o * HIDD + j0 + jj];
    pre[jj] = acc;
  }
  {
    float s1 = pre[0] + pre[1];
    float s2 = pre[0] * pre[0] + pre[1] * pre[1];
    s1 += __shfl_xor(s1, 1, 16); s1 += __shfl_xor(s1, 2, 16);
    s1 += __shfl_xor(s1, 4, 16); s1 += __shfl_xor(s1, 8, 16);
    s2 += __shfl_xor(s2, 1, 16); s2 += __shfl_xor(s2, 2, 16);
    s2 += __shfl_xor(s2, 4, 16); s2 += __shfl_xor(s2, 8, 16);
    float mean = s1 * (1.f / 32.f);
    float var = s2 * (1.f / 32.f) - mean * mean;
    float r = rsqrtf(var + 1e-5f);
#pragma unroll
    for (int jj = 0; jj < 2; ++jj)
      pre[jj] = (pre[jj] - mean) * r * sp_g[j0 + jj] + sp_b[j0 + jj];
  }
  *(float2*)(h_out + (size_t)row * HIDD + j0) = make_float2(pre[0], pre[1]);
  float t1[24];
#pragma unroll
  for (int o = 0; o < 24; ++o) {
    float acc = pre[0] * qkv_lo_w[j0 * 24 + o] + pre[1] * qkv_lo_w[(j0 + 1) * 24 + o];
    acc += __shfl_xor(acc, 1, 16); acc += __shfl_xor(acc, 2, 16);
    acc += __shfl_xor(acc, 4, 16); acc += __shfl_xor(acc, 8, 16);
    t1[o] = acc + qkv_lo_b[o];
  }
  const float scl = 0.35355339059327373f;  // 1/sqrt(8)
  int sub = l >> 3, d = l & 7;
#pragma unroll
  for (int part = 0; part < 3; ++part) {
#pragma unroll
    for (int hh = 0; hh < 2; ++hh) {
      int hd = sub * 2 + hh;
      int p = part * 32 + hd * 8 + d;
      float acc = qkv_hi_b[p];
#pragma unroll
      for (int o = 0; o < 24; ++o) acc += t1[o] * qkv_hi_w[o * 96 + p];
      int bh = b * NHEADS + hd;
      if (part == 0) {
        Qh[((size_t)bh * PROWS + n) * 16 + d] = (f16)(acc * scl);
        Qh[((size_t)bh * PROWS + n) * 16 + 8 + d] = (f16)gU[n * 8 + d];
      } else if (part == 1) {
        Kh[((size_t)bh * PROWS + n) * 16 + d] = (f16)acc;
        Kh[((size_t)bh * PROWS + n) * 16 + 8 + d] = (f16)VgT[n * 8 + d];
      } else {
        VT[((size_t)bh * 16 + d) * PROWS + n] = (f16)acc;
        Vh[((size_t)bh * PROWS + n) * 8 + d] = (f16)acc;
      }
    }
  }
}

// ---------------- attention: dense MFMA tiles (y<24) + sparse adj correction (y>=24) ----
__global__ void __launch_bounds__(256, 4)
k_attn(const f16* __restrict__ Qh, const f16* __restrict__ Kh,
       const f16* __restrict__ VT, const f16* __restrict__ Vh,
       const int* __restrict__ sidx, const float* __restrict__ sraw,
       const int* __restrict__ scnt,
       const float* __restrict__ adj_mix, const float* __restrict__ adj_scale,
       float* __restrict__ P) {
  int bh = blockIdx.x;
  int tid = threadIdx.x;
  __shared__ f16 Ks[MC * KS_STRIDE];   // 6 KB
  __shared__ f16 Vs[16 * VS_STRIDE];   // 4.3 KB
  if (blockIdx.y < 24) {
    int tile = blockIdx.y;
    int wave = tid >> 6, lane = tid & 63;
    int quad = lane >> 4, l16 = lane & 15;
    int n0 = tile * 64 + wave * 16;
    half4 qf = *(const half4*)(Qh + ((size_t)bh * PROWS + n0 + l16) * 16 + quad * 4);
    floatx4 acc = {0.f, 0.f, 0.f, 0.f};
    for (int m0 = 0; m0 < PROWS; m0 += MC) {
      __syncthreads();
      {
        int row = tid >> 1, h = (tid & 1) * 8;
        *(float4*)(Ks + row * KS_STRIDE + h) =
            *(const float4*)(Kh + ((size_t)bh * PROWS + m0 + row) * 16 + h);
        int d = tid >> 4, c = (tid & 15) * 8;
        *(float4*)(Vs + d * VS_STRIDE + c) =
            *(const float4*)(VT + ((size_t)bh * 16 + d) * PROWS + m0 + c);
      }
      __syncthreads();
#pragma unroll
      for (int mt = 0; mt < MC / 16; ++mt) {
        half4 kf = *(const half4*)(Ks + (mt * 16 + l16) * KS_STRIDE + quad * 4);
        floatx4 s = __builtin_amdgcn_mfma_f32_16x16x16f16(
            kf, qf, (floatx4){0.f, 0.f, 0.f, 0.f}, 0, 0, 0);
        half4 pf;
        pf[0] = (f16)__expf(s[0]);
        pf[1] = (f16)__expf(s[1]);
        pf[2] = (f16)__expf(s[2]);
        pf[3] = (f16)__expf(s[3]);
        half4 vf = *(const half4*)(Vs + l16 * VS_STRIDE + mt * 16 + quad * 4);
        acc = __builtin_amdgcn_mfma_f32_16x16x16f16(pf, vf, acc, 0, 0, 0);
      }
    }
    if (l16 < 9) {
#pragma unroll
      for (int r = 0; r < 4; ++r) {
        int n = n0 + quad * 4 + r;
        P[((size_t)bh * PROWS + n) * 12 + l16] = acc[r];
      }
    }
  } else {
    // sparse adjacency correction -> partial slot 1 (vectorized f16 loads)
    int ytile = blockIdx.y - 24;
    int g = tid >> 3, p = tid & 7;
    float smix = adj_scale[0] / (1.f + __expf(-adj_mix[0]));
    for (int rr = 0; rr < 4; ++rr) {
      int n = ytile * 128 + g * 4 + rr;
      float acc[8] = {0.f, 0.f, 0.f, 0.f, 0.f, 0.f, 0.f, 0.f};
      float sm = 0.f;
      if (n < NN) {
        half4 q0 = *(const half4*)(Qh + ((size_t)bh * PROWS + n) * 16);
        half4 q1 = *(const half4*)(Qh + ((size_t)bh * PROWS + n) * 16 + 4);
        half4 q2 = *(const half4*)(Qh + ((size_t)bh * PROWS + n) * 16 + 8);
        half4 q3 = *(const half4*)(Qh + ((size_t)bh * PROWS + n) * 16 + 12);
        int cnt = scnt[n];
        for (int e = p; e < cnt; e += 8) {
          int m = sidx[n * CAP + e];
          float a = sraw[n * CAP + e];
          if (a != 0.f) {
            const f16* kp = Kh + ((size_t)bh * PROWS + m) * 16;
            half4 k0 = *(const half4*)(kp);
            half4 k1 = *(const half4*)(kp + 4);
            half4 k2 = *(const half4*)(kp + 8);
            half4 k3 = *(const half4*)(kp + 12);
            float s = 0.f;
#pragma unroll
            for (int d = 0; d < 4; ++d)
              s += (float)q0[d] * (float)k0[d] + (float)q1[d] * (float)k1[d]
                 + (float)q2[d] * (float)k2[d] + (float)q3[d] * (float)k3[d];
            float ep = __expf(s);
            float dlt = ep * (__expf(smix * a) - 1.f);
            sm += dlt;
            const f16* vp = Vh + ((size_t)bh * PROWS + m) * 8;
            half4 v0 = *(const half4*)(vp);
            half4 v1 = *(const half4*)(vp + 4);
#pragma unroll
            for (int d = 0; d < 4; ++d) {
              acc[d] += dlt * (float)v0[d];
              acc[4 + d] += dlt * (float)v1[d];
            }
          }
        }
      }
      sm += __shfl_xor(sm, 1, 8); sm += __shfl_xor(sm, 2, 8); sm += __shfl_xor(sm, 4, 8);
#pragma unroll
      for (int d = 0; d < 8; ++d) {
        acc[d] += __shfl_xor(acc[d], 1, 8);
        acc[d] += __shfl_xor(acc[d], 2, 8);
        acc[d] += __shfl_xor(acc[d], 4, 8);
      }
      float val = acc[0];
#pragma unroll
      for (int d = 1; d < 8; ++d) if (p == d) val = acc[d];
      if (n < NN) {
        float* dst = P + ((size_t)(32 + bh) * PROWS + n) * 12;
        dst[p] = val;
        if (p == 0) dst[8] = sm;
      }
    }
  }
}

// ---------------- merge partials + output proj + at_ln + gated predictor: 8 lanes/row ----
__global__ void k_final(const float* __restrict__ P, const float* __restrict__ h_in,
    const float* __restrict__ x,
    const float* __restrict__ out_lo_w, const float* __restrict__ out_lo_b,
    const float* __restrict__ out_hi_w, const float* __restrict__ out_hi_b,
    const float* __restrict__ at_g, const float* __restrict__ at_b,
    const float* __restrict__ pred_lo_w, const float* __restrict__ pred_lo_b,
    const float* __restrict__ mid_g, const float* __restrict__ mid_b,
    const float* __restrict__ pred_hi_w, const float* __restrict__ pred_hi_b,
    const float* __restrict__ log_decay,
    const float* __restrict__ gate_w1, const float* __restrict__ gate_b1,
    const float* __restrict__ gate_w2, const float* __restrict__ gate_b2,
    float* __restrict__ out) {
  int tid = threadIdx.x;
  int gr = tid >> 3, l = tid & 7;
  int row = blockIdx.x * 32 + gr;   // 375 blocks * 32 rows = 12000
  int b = row / NN, n = row % NN;
  int j0 = 4 * l;
  int hd = l >> 1, d0 = (l & 1) * 4;
  int bh = b * NHEADS + hd;
  float av[4] = {0.f, 0.f, 0.f, 0.f};
  float smt = 0.f;
#pragma unroll
  for (int z = 0; z < 2; ++z) {
    const float* q = P + ((size_t)(z * 32 + bh) * PROWS + n) * 12;
    float4 a4 = *(const float4*)(q + d0);
    av[0] += a4.x; av[1] += a4.y; av[2] += a4.z; av[3] += a4.w;
    smt += q[8];
  }
  float oinv = 1.f / smt;
  float ov4[4];
#pragma unroll
  for (int d = 0; d < 4; ++d) ov4[d] = av[d] * oinv;
  float lo[BOTT];
#pragma unroll
  for (int o = 0; o < BOTT; ++o) {
    float acc = 0.f;
#pragma unroll
    for (int jj = 0; jj < 4; ++jj) acc += ov4[jj] * out_lo_w[(j0 + jj) * BOTT + o];
    acc += __shfl_xor(acc, 1, 8); acc += __shfl_xor(acc, 2, 8); acc += __shfl_xor(acc, 4, 8);
    lo[o] = acc + out_lo_b[o];
  }
  float4 hin4 = *(const float4*)(h_in + (size_t)row * HIDD + j0);
  float pre[4] = {hin4.x, hin4.y, hin4.z, hin4.w};
#pragma unroll
  for (int jj = 0; jj < 4; ++jj) {
    float acc = out_hi_b[j0 + jj] + pre[jj];
#pragma unroll
    for (int o = 0; o < BOTT; ++o) acc += lo[o] * out_hi_w[o * HIDD + j0 + jj];
    pre[jj] = acc;
  }
  float h2[4];
  {
    float s1 = pre[0] + pre[1] + pre[2] + pre[3];
    float s2 = pre[0]*pre[0] + pre[1]*pre[1] + pre[2]*pre[2] + pre[3]*pre[3];
    s1 += __shfl_xor(s1, 1, 8); s1 += __shfl_xor(s1, 2, 8); s1 += __shfl_xor(s1, 4, 8);
    s2 += __shfl_xor(s2, 1, 8); s2 += __shfl_xor(s2, 2, 8); s2 += __shfl_xor(s2, 4, 8);
    float mean = s1 * (1.f / 32.f);
    float var = s2 * (1.f / 32.f) - mean * mean;
    float r = rsqrtf(var + 1e-5f);
#pragma unroll
    for (int jj = 0; jj < 4; ++jj)
      h2[jj] = (pre[jj] - mean) * r * at_g[j0 + jj] + at_b[j0 + jj];
  }
  float pl[BOTT];
#pragma unroll
  for (int o = 0; o < BOTT; ++o) {
    float acc = 0.f;
#pragma unroll
    for (int jj = 0; jj < 4; ++jj) acc += h2[jj] * pred_lo_w[(j0 + jj) * BOTT + o];
    acc += __shfl_xor(acc, 1, 8); acc += __shfl_xor(acc, 2, 8); acc += __shfl_xor(acc, 4, 8);
    pl[o] = acc + pred_lo_b[o];
  }
  float xm[BOTT];
  {
    float m = 0.f;
#pragma unroll
    for (int o = 0; o < BOTT; ++o) m += pl[o];
    m *= (1.f / BOTT);
    float var = 0.f;
#pragma unroll
    for (int o = 0; o < BOTT; ++o) { float d = pl[o] - m; var += d * d; }
    var *= (1.f / BOTT);
    float r = rsqrtf(var + 1e-5f);
#pragma unroll
    for (int o = 0; o < BOTT; ++o)
      xm[o] = fmaxf((pl[o] - m) * r * mid_g[o] + mid_b[o], 0.f);
  }
  float ga[BOTT];
#pragma unroll
  for (int o = 0; o < BOTT; ++o) {
    float acc = 0.f;
#pragma unroll
    for (int jj = 0; jj < 4; ++jj) acc += h2[jj] * gate_w1[(j0 + jj) * BOTT + o];
    acc += __shfl_xor(acc, 1, 8); acc += __shfl_xor(acc, 2, 8); acc += __shfl_xor(acc, 4, 8);
    ga[o] = fmaxf(acc + gate_b1[o], 0.f);
  }
  float xl = x[(size_t)b * TT * NN + (size_t)(TT - 1) * NN + n];
  float dec = __expf(log_decay[0]);
#pragma unroll
  for (int ii = 0; ii < 2; ++ii) {
    int i = l + ii * 8;
    if (i < HZNN) {
      float accp = pred_hi_b[i];
#pragma unroll
      for (int o = 0; o < BOTT; ++o) accp += xm[o] * pred_hi_w[o * HZNN + i];
      float accg = gate_b2[i];
#pragma unroll
      for (int o = 0; o < BOTT; ++o) accg += ga[o] * gate_w2[o * HZNN + i];
      float gt = 1.f / (1.f + __expf(-accg));
      float pr = xl * __expf(-dec * (float)(i + 1));
      out[(size_t)row * HZNN + i] = gt * accp + (1.f - gt) * pr;
    }
  }
}

extern "C" void kernel_launch(void* const* d_in, const int* in_sizes, int n_in,
                              void* d_out, int out_size, void* d_ws, size_t ws_size,
                              hipStream_t stream) {
  const float* x          = (const float*)d_in[0];
  const float* adj        = (const float*)d_in[1];
  const float* dw_w       = (const float*)d_in[2];
  const float* dw_b       = (const float*)d_in[3];
  const float* bn1_g      = (const float*)d_in[4];
  const float* bn1_b      = (const float*)d_in[5];
  const float* pw_w       = (const float*)d_in[6];
  const float* pw_b       = (const float*)d_in[7];
  const float* bn2_g      = (const float*)d_in[8];
  const float* bn2_b      = (const float*)d_in[9];
  const float* feat_w     = (const float*)d_in[10];
  const float* feat_b     = (const float*)d_in[11];
  const float* scale_w    = (const float*)d_in[12];
  const float* scale_b    = (const float*)d_in[13];
  const float* scale_ln_g = (const float*)d_in[14];
  const float* scale_ln_b = (const float*)d_in[15];
  const float* fusion_w   = (const float*)d_in[16];
  const float* fus_lo_w   = (const float*)d_in[17];
  const float* fus_lo_b   = (const float*)d_in[18];
  const float* fus_hi_w   = (const float*)d_in[19];
  const float* fus_hi_b   = (const float*)d_in[20];
  const float* sp_ln_g    = (const float*)d_in[21];
  const float* sp_ln_b    = (const float*)d_in[22];
  const float* qkv_lo_w   = (const float*)d_in[23];
  const float* qkv_lo_b   = (const float*)d_in[24];
  const float* qkv_hi_w   = (const float*)d_in[25];
  const float* qkv_hi_b   = (const float*)d_in[26];
  const float* graph_U    = (const float*)d_in[27];
  const float* graph_V    = (const float*)d_in[28];
  const float* adj_mix    = (const float*)d_in[29];
  const float* adj_scale  = (const float*)d_in[30];
  const float* out_lo_w   = (const float*)d_in[31];
  const float* out_lo_b   = (const float*)d_in[32];
  const float* out_hi_w   = (const float*)d_in[33];
  const float* out_hi_b   = (const float*)d_in[34];
  const float* at_ln_g    = (const float*)d_in[35];
  const float* at_ln_b    = (const float*)d_in[36];
  const float* pred_lo_w  = (const float*)d_in[37];
  const float* pred_lo_b  = (const float*)d_in[38];
  const float* mid_ln_g   = (const float*)d_in[39];
  const float* mid_ln_b   = (const float*)d_in[40];
  const float* pred_hi_w  = (const float*)d_in[41];
  const float* pred_hi_b  = (const float*)d_in[42];
  const float* log_decay  = (const float*)d_in[43];
  const float* gate_w1    = (const float*)d_in[44];
  const float* gate_b1    = (const float*)d_in[45];
  const float* gate_w2    = (const float*)d_in[46];
  const float* gate_b2    = (const float*)d_in[47];

  float* ws = (float*)d_ws;
  float* h0    = ws;                       // [N][256]
  float* g1    = h0 + (size_t)NN * BC;
  float* g2    = g1 + (size_t)NN * BC;
  float* g3    = g2 + (size_t)NN * BC;
  float* hfull = g3 + (size_t)NN * BC;     // [B*N][32]
  float* VgT   = hfull + (size_t)BB * NN * HIDD;   // [N][8]
  float* sval  = VgT + (size_t)NN * 8;             // [N][CAP]
  float* sraw  = sval + (size_t)NN * CAP;          // [N][CAP]
  int*   sidx  = (int*)(sraw + (size_t)NN * CAP);  // [N][CAP]
  int*   scnt  = sidx + (size_t)NN * CAP;          // [N]
  float* P     = (float*)(scnt + NN + 3);          // [2][32][PROWS][12]
  P = (float*)(((uintptr_t)P + 15) & ~(uintptr_t)15);
  f16* Qh = (f16*)(P + (size_t)2 * 32 * PROWS * 12);   // [32][PROWS][16]
  f16* Kh = Qh + (size_t)32 * PROWS * 16;              // [32][PROWS][16]
  f16* VT = Kh + (size_t)32 * PROWS * 16;              // [32][16][PROWS]
  f16* Vh = VT + (size_t)32 * 16 * PROWS;              // [32][PROWS][8]

  k_prep_temporal<<<NN + 47, 256, 0, stream>>>(
      adj, graph_V, sidx, sval, sraw, scnt, VgT, Qh, Kh, VT, Vh,
      x, dw_w, dw_b, bn1_g, bn1_b, pw_w, pw_b, bn2_g, bn2_b, feat_w, feat_b, h0);
  k_spmm_sp<<<NN, 256, 0, stream>>>(sidx, sval, scnt, h0, g1);
  k_spmm_sp<<<NN, 256, 0, stream>>>(sidx, sval, scnt, g1, g2);
  k_spmm_sp<<<NN, 256, 0, stream>>>(sidx, sval, scnt, g2, g3);
  k_fuse_qkv<<<(BB * NN) / 16, 256, 0, stream>>>(
      h0, g1, g2, g3, scale_w, scale_b, scale_ln_g, scale_ln_b, fusion_w,
      fus_lo_w, fus_lo_b, fus_hi_w, fus_hi_b, sp_ln_g, sp_ln_b,
      qkv_lo_w, qkv_lo_b, qkv_hi_w, qkv_hi_b, graph_U, VgT,
      hfull, Qh, Kh, VT, Vh);
  k_attn<<<dim3(32, 36), 256, 0, stream>>>(
      Qh, Kh, VT, Vh, sidx, sraw, scnt, adj_mix, adj_scale, P);
  k_final<<<(BB * NN) / 32, 256, 0, stream>>>(
      P, hfull, x, out_lo_w, out_lo_b, out_hi_w, out_hi_b, at_ln_g, at_ln_b,
      pred_lo_w, pred_lo_b, mid_ln_g, mid_ln_b, pred_hi_w, pred_hi_b,
      log_decay, gate_w1, gate_b1, gate_w2, gate_b2, (float*)d_out);
}